// Round 7
// baseline (190.367 us; speedup 1.0000x reference)
//
#include <hip/hip_runtime.h>
#include <cstdint>
#include <cstddef>

// MultiHeadAttention R17:
//   gemm_qkv unchanged (256x256 8-wave phase-split, 3-bit XOR swizzle).
//   attn_mfma unchanged from R16 (unpaired q-groups, triple-buf vmcnt(4),
//   v_exp_f32 asm) -- pinned at 52us across 5 variants; parked.
//   OUT-PROJECTION re-tiled: gemm_bt<0> ran 256 blocks on 256 CUs = 1
//   block/CU, 1 wave/SIMD -- zero latency hiding, ~150 TF, est ~55-60us
//   (largest kernel, hidden just under attn in top-5). New gemm_out:
//   128x64 tiles -> 512 blocks = 2 blocks/CU, 2 waves/SIMD (the occupancy
//   at which the same structure measured 427 TF). Triple-buffered K-loop,
//   counted vmcnt(3) (3 GLDS/thread/stage: A=2, B=1), staging/read swizzle
//   pair copied verbatim from the proven 128^2 kernel. K order and per-
//   output MFMA sequence unchanged -> bitwise-identical output.
// ws layout (bytes):
//   xb @0 [4096][1024] bf16 | wqb @8388608 [3072][1024] | wob @14680064 [1024][1024]
//   Qb @16777216, Kb @25165824: [2][16][2048][64] bf16 (Qb = Q*log2e)
//   Vt @33554432: [2][16][64][2048] bf16 (transposed)
//   CTX @41943040 [4096][1024] bf16
// MFMA 16x16x32_bf16 frags: A[m=lane&15][k=quad*8+i], B[n=lane&15][k=quad*8+i],
// C/D[row=quad*4+reg][col=lane&15]. Swapped operands -> D = C^T.

typedef __attribute__((ext_vector_type(8))) short bf16x8;
typedef __attribute__((ext_vector_type(4))) float f32x4;

#define LOG2E 1.44269504f

#define MFMA16(a, b, c) __builtin_amdgcn_mfma_f32_16x16x32_bf16((a), (b), (c), 0, 0, 0)

#define GLDS16(g, s)                                                        \
  __builtin_amdgcn_global_load_lds(                                         \
      (const __attribute__((address_space(1))) void*)(g),                   \
      (__attribute__((address_space(3))) void*)(s), 16, 0, 0)

// Manual barrier: wait until <= N vector-memory ops outstanding, then barrier.
// ONLY valid when the loop's vmem traffic is exclusively the staged GLDS.
#define ASYNC_BAR(N) asm volatile("s_waitcnt vmcnt(" #N ")\n\ts_barrier" ::: "memory")
#define BAR() asm volatile("s_barrier" ::: "memory")

// Native 2^x: v_exp_f32 (gfx950 VOP1). Input already in log2 domain.
static __device__ __forceinline__ float exp2_hw(float x) {
  float r;
  asm("v_exp_f32 %0, %1" : "=v"(r) : "v"(x));
  return r;
}
#define EXP2F(x) exp2_hw(x)

static __device__ __forceinline__ unsigned short f2bf(float f) {  // RNE
  unsigned int u = __builtin_bit_cast(unsigned int, f);
  u += 0x7FFFu + ((u >> 16) & 1u);
  return (unsigned short)(u >> 16);
}

// pack two fp32 -> two bf16 (round-nearest) in one u32: 2 add + 1 perm
static __device__ __forceinline__ unsigned int pk2bf(float a, float b) {
  const unsigned int ua = __builtin_bit_cast(unsigned int, a) + 0x8000u;
  const unsigned int ub = __builtin_bit_cast(unsigned int, b) + 0x8000u;
  return __builtin_amdgcn_perm(ub, ua, 0x07060302);
}

// ---------------------------------------------------------------------------
__global__ __launch_bounds__(256) void cast_bf16(const float* __restrict__ x,
                                                 const float* __restrict__ wq,
                                                 const float* __restrict__ wo,
                                                 unsigned short* __restrict__ xb,
                                                 unsigned short* __restrict__ wqb,
                                                 unsigned short* __restrict__ wob)
{
  const int id = blockIdx.x * 256 + threadIdx.x;
  const float* src;
  unsigned short* dst;
  int off;
  if (id < 1048576)               { src = x;  dst = xb;  off = id; }
  else if (id < 1048576 + 786432) { src = wq; dst = wqb; off = id - 1048576; }
  else                            { src = wo; dst = wob; off = id - (1048576 + 786432); }
  float4 v = ((const float4*)src)[off];
  ushort4 o;
  o.x = f2bf(v.x); o.y = f2bf(v.y); o.z = f2bf(v.z); o.w = f2bf(v.w);
  ((ushort4*)dst)[off] = o;
}

// ---------------------------------------------------------------------------
// QKV GEMM (unchanged R12): 256x256 tile, BK=64, 512 threads = 8 waves
// (2M x 4N), per-wave 128x64 output (acc[8][4] of 16x16 frags).
// LDS 128 KiB: 2 buffers x (A 256x64 | B 256x64) bf16, rows of 128B split
// into 8x16B slots, phys_slot = logical_slot ^ (row & 7)   [FULL 3-bit XOR].
// 4 phases per K-tile, 16 MFMA each; ONE vmcnt(4) per K-tile.
// ---------------------------------------------------------------------------
#define MMAC(AF, BF, MS, NS)                                                       \
  do {                                                                             \
    __builtin_amdgcn_s_setprio(1);                                                 \
    if (swapped) {                                                                 \
      _Pragma("unroll")                                                            \
      for (int mt = 0; mt < 4; ++mt)                                               \
        _Pragma("unroll")                                                          \
        for (int nt = 0; nt < 2; ++nt) {                                           \
          acc[(MS)*4+mt][(NS)*2+nt] = MFMA16(BF[nt][0], AF[mt][0], acc[(MS)*4+mt][(NS)*2+nt]); \
          acc[(MS)*4+mt][(NS)*2+nt] = MFMA16(BF[nt][1], AF[mt][1], acc[(MS)*4+mt][(NS)*2+nt]); \
        }                                                                          \
    } else {                                                                       \
      _Pragma("unroll")                                                            \
      for (int mt = 0; mt < 4; ++mt)                                               \
        _Pragma("unroll")                                                          \
        for (int nt = 0; nt < 2; ++nt) {                                           \
          acc[(MS)*4+mt][(NS)*2+nt] = MFMA16(AF[mt][0], BF[nt][0], acc[(MS)*4+mt][(NS)*2+nt]); \
          acc[(MS)*4+mt][(NS)*2+nt] = MFMA16(AF[mt][1], BF[nt][1], acc[(MS)*4+mt][(NS)*2+nt]); \
        }                                                                          \
    }                                                                              \
    __builtin_amdgcn_s_setprio(0);                                                 \
  } while (0)

__global__ __launch_bounds__(512, 2) void gemm_qkv(const unsigned short* __restrict__ A,
                                                   const unsigned short* __restrict__ B,
                                                   unsigned short* __restrict__ Qb,
                                                   unsigned short* __restrict__ Kb,
                                                   unsigned short* __restrict__ Vt)
{
  // shorts: buf b: A @ b*32768 (256 rows x 64), B @ b*32768+16384. 128 KiB.
  __shared__ unsigned short pool[65536];

  const int tid  = threadIdx.x;
  const int wave = tid >> 6, lane = tid & 63, quad = lane >> 4, cl = lane & 15;
  const int wm = wave >> 2, wn = wave & 3;

  // Bijective XCD chunking: 192 blocks, 24/XCD covering a 4(mb) x 6(nb) chunk.
  const int bid = blockIdx.x;
  const int xcd = bid & 7, j = bid >> 3;
  const int mb = (xcd >> 1) * 4 + j / 6;
  const int nb = (xcd & 1) * 6 + j % 6;
  const int m0 = mb * 256, n0 = nb * 256;
  const int part = nb >> 2;                 // 0=Q 1=K 2=V
  const bool swapped = (part < 2);

  // --- staging: per GLDS16, wave covers 8 rows x 128B linearly.
  // lane l -> row r0+(l>>3), phys slot l&7. Pre-swizzled global source:
  // logical slot = phys ^ (row&7) = (l&7) ^ (l>>3)   [r0 is a multiple of 8]
  const int lrow = lane >> 3;
  const int sg   = (lane & 7) ^ lrow;

  auto stageA = [&](int h0, int buf, int k0) {
    #pragma unroll
    for (int ii = 0; ii < 2; ++ii) {
      const int r0 = h0 + wave * 16 + ii * 8;
      GLDS16(A + (size_t)(m0 + r0 + lrow) * 1024 + k0 + sg * 8,
             &pool[buf * 32768 + r0 * 64]);
    }
  };
  auto stageB = [&](int h0, int buf, int k0) {
    #pragma unroll
    for (int ii = 0; ii < 2; ++ii) {
      const int r0 = h0 + wave * 16 + ii * 8;
      GLDS16(B + (size_t)(n0 + r0 + lrow) * 1024 + k0 + sg * 8,
             &pool[buf * 32768 + 16384 + r0 * 64]);
    }
  };

  // --- fragment reads: row = 16-aligned base + cl -> row&7 == cl&7.
  // logical k-chunk (kk*4+quad) lives at phys slot (kk*4+quad) ^ (cl&7).
  const int rswz = cl & 7;
  auto loadA = [&](bf16x8 (&af)[4][2], int msub, int b) {
    const unsigned short* base = &pool[b * 32768];
    #pragma unroll
    for (int mt = 0; mt < 4; ++mt) {
      const int row = wm * 128 + msub * 64 + mt * 16 + cl;
      #pragma unroll
      for (int kk = 0; kk < 2; ++kk)
        af[mt][kk] = *(const bf16x8*)&base[row * 64 + ((kk * 4 + quad) ^ rswz) * 8];
    }
  };
  auto loadB = [&](bf16x8 (&bf)[2][2], int nsub, int b) {
    const unsigned short* base = &pool[b * 32768 + 16384];
    #pragma unroll
    for (int nt = 0; nt < 2; ++nt) {
      const int row = wn * 64 + nsub * 32 + nt * 16 + cl;
      #pragma unroll
      for (int kk = 0; kk < 2; ++kk)
        bf[nt][kk] = *(const bf16x8*)&base[row * 64 + ((kk * 4 + quad) ^ rswz) * 8];
    }
  };

  f32x4 acc[8][4];
  #pragma unroll
  for (int i = 0; i < 8; ++i)
    #pragma unroll
    for (int jj = 0; jj < 4; ++jj)
      #pragma unroll
      for (int r = 0; r < 4; ++r) acc[i][jj][r] = 0.f;

  // Prologue: all 4 half-tiles of tile0, then lo halves of tile1 (12 loads).
  stageB(0,   0, 0);
  stageA(0,   0, 0);
  stageB(128, 0, 0);
  stageA(128, 0, 0);
  stageB(0,   1, 64);
  stageA(0,   1, 64);

  #pragma unroll 1
  for (int t = 0; t < 16; ++t) {
    const int b = t & 1, bn = b ^ 1;
    const int kc  = (t + 1) * 64;
    const int kc2 = (t + 2) * 64;

    bf16x8 af[4][2], bfA[2][2], bfB[2][2];

    // P0: quadrant (0,0). vmcnt(4): guarantees all 4 halves of tile t
    // (newest needed = A-hi(t) @ (t-1)-P1; newer in flight = B-lo/A-lo(t+1)).
    if (t < 15) { ASYNC_BAR(4); } else { ASYNC_BAR(0); }
    loadA(af, 0, b);
    loadB(bfA, 0, b);
    if (t < 15) stageB(128, bn, kc);       // B-hi(t+1)
    MMAC(af, bfA, 0, 0);

    // P1: quadrant (0,1). No barrier needed: reads tile-t B (published at P0),
    // GLDS writes buffer bn (not being read).
    loadB(bfB, 1, b);
    if (t < 15) stageA(128, bn, kc);       // A-hi(t+1)
    MMAC(af, bfB, 0, 1);

    // P2: quadrant (1,1). Barrier: B-lo(t+2) overwrites B-lo(b) whose last
    // reads were P1 (other waves).
    BAR();
    loadA(af, 1, b);
    if (t < 14) stageB(0, b, kc2);         // B-lo(t+2)
    MMAC(af, bfB, 1, 1);

    // P3: quadrant (1,0), reuses bfA regs. Barrier: A-lo(t+2) overwrites
    // A-lo(b) whose last reads were P2 (wm=0 waves).
    BAR();
    if (t < 14) stageA(0, b, kc2);         // A-lo(t+2)
    MMAC(af, bfA, 1, 0);
  }
  // ASYNC_BAR(0) at t=15-P0 drained all staging: no GLDS in flight here.

  const int bb = m0 >> 11, ss = m0 & 2047;
  if (part < 2) {
    // Q/K (swapped: D=C^T): lane holds 4 consecutive d for one s -> ushort4
    unsigned short* dst = (part == 0) ? Qb : Kb;
    const float sc2 = (part == 0) ? LOG2E : 1.0f;
    const int npb = (n0 & 1023) + wn * 64;
    #pragma unroll
    for (int mt = 0; mt < 8; ++mt) {
      const int m = ss + wm * 128 + mt * 16 + cl;
      #pragma unroll
      for (int nt = 0; nt < 4; ++nt) {
        const int np = npb + nt * 16 + quad * 4;
        const int hh = np >> 6, d0 = np & 63;
        ushort4 pk;
        pk.x = f2bf(acc[mt][nt][0] * sc2);
        pk.y = f2bf(acc[mt][nt][1] * sc2);
        pk.z = f2bf(acc[mt][nt][2] * sc2);
        pk.w = f2bf(acc[mt][nt][3] * sc2);
        *(ushort4*)&dst[((size_t)(bb * 16 + hh) * 2048 + m) * 64 + d0] = pk;
      }
    }
  } else {
    // V (normal orientation): transpose through LDS (reuse pool),
    // trans[128][264] shorts per round; 2 rounds (wn pairs).
    unsigned short* trans = pool;
    #pragma unroll 1
    for (int r = 0; r < 2; ++r) {
      __syncthreads();
      if ((wn >> 1) == r) {
        #pragma unroll
        for (int mt = 0; mt < 8; ++mt) {
          const int s_l = wm * 128 + mt * 16 + quad * 4;
          #pragma unroll
          for (int nt = 0; nt < 4; ++nt) {
            const int n_l = (wn & 1) * 64 + nt * 16 + cl;
            ushort4 pk;
            pk.x = f2bf(acc[mt][nt][0]); pk.y = f2bf(acc[mt][nt][1]);
            pk.z = f2bf(acc[mt][nt][2]); pk.w = f2bf(acc[mt][nt][3]);
            *(ushort4*)&trans[n_l * 264 + s_l] = pk;
          }
        }
      }
      __syncthreads();
      const int row = tid >> 2, q4 = tid & 3;
      const int nv = (n0 & 1023) + r * 128 + row;
      const int hh = nv >> 6, d = nv & 63;
      unsigned short* drow = Vt + ((size_t)(bb * 16 + hh) * 64 + d) * 2048 + ss + q4 * 64;
      #pragma unroll
      for (int i = 0; i < 8; ++i)
        *(bf16x8*)(drow + i * 8) = *(const bf16x8*)&trans[row * 264 + q4 * 64 + i * 8];
    }
  }
}

// ---------------------------------------------------------------------------
// Out-projection R17: 128(M) x 64(N) tile, 256 threads (4 waves, each owns
// 32x64 = acc[2][4]). Grid 16x32 = 512 blocks = 2 blocks/CU (was 256 = 1).
// Triple-buffered K-loop (BK=32), counted vmcnt(3): each stage issues 3
// GLDS/thread (A: 2, B: 1). Staging/read swizzle identical to the proven
// 128^2 kernel (scs <-> rchunk involution). K order and per-output MFMA
// sequence unchanged vs gemm_bt<0> -> bitwise-identical output.
// LDS: 3 stages x (A 128x32 | B 64x32) shorts = 18432 shorts = 36 KiB.
// ---------------------------------------------------------------------------
__global__ __launch_bounds__(256) void gemm_out(const unsigned short* __restrict__ A,
                                                const unsigned short* __restrict__ B,
                                                const float* __restrict__ bias,
                                                float* __restrict__ OutF)
{
  __shared__ unsigned short pool[18432];   // 3 x (A 4096 | B 2048) shorts

  const int tid  = threadIdx.x;
  const int wave = tid >> 6, lane = tid & 63, quad = lane >> 4, cl = lane & 15;
  const int m0 = blockIdx.y * 128, n0 = blockIdx.x * 64;
  const int sr = lane >> 2, sc = lane & 3;

  f32x4 acc[2][4];
  #pragma unroll
  for (int i = 0; i < 2; ++i)
    #pragma unroll
    for (int j = 0; j < 4; ++j)
      #pragma unroll
      for (int r = 0; r < 4; ++r) acc[i][j][r] = 0.f;

  const int scs = (sc ^ ((sr >> 1) & 3)) * 8;
  const int rchunk = (quad ^ ((cl >> 1) & 3)) * 8;

  auto stage = [&](int k0, int buf) {
    unsigned short* As = pool + buf * 6144;
    unsigned short* Bs = As + 4096;
    #pragma unroll
    for (int ii = 0; ii < 2; ++ii) {
      const int r = wave * 32 + ii * 16 + sr;
      GLDS16(A + (size_t)(m0 + r) * 1024 + k0 + scs, &As[(wave * 32 + ii * 16) * 32]);
    }
    const int rB = wave * 16 + sr;
    GLDS16(B + (size_t)(n0 + rB) * 1024 + k0 + scs, &Bs[(wave * 16) * 32]);
  };

  stage(0, 0);
  stage(32, 1);
  int cur = 0;
  #pragma unroll 1
  for (int it = 0; it < 32; ++it) {
    if (it + 2 < 32) {
      ASYNC_BAR(3);                              // drain stage(it); keep stage(it+1)
      const int bnx = (cur == 0) ? 2 : cur - 1;  // (cur+2)%3
      stage((it + 2) * 32, bnx);
    } else if (it + 1 < 32) {
      ASYNC_BAR(3);
    } else {
      ASYNC_BAR(0);
    }

    const unsigned short* As = pool + cur * 6144;
    const unsigned short* Bs = As + 4096;
    bf16x8 af[2], bfr[4];
    #pragma unroll
    for (int mt = 0; mt < 2; ++mt)
      af[mt] = *(const bf16x8*)&As[(wave * 32 + mt * 16 + cl) * 32 + rchunk];
    #pragma unroll
    for (int nt = 0; nt < 4; ++nt)
      bfr[nt] = *(const bf16x8*)&Bs[(nt * 16 + cl) * 32 + rchunk];

    __builtin_amdgcn_s_setprio(1);
    #pragma unroll
    for (int mt = 0; mt < 2; ++mt)
      #pragma unroll
      for (int nt = 0; nt < 4; ++nt)
        acc[mt][nt] = MFMA16(bfr[nt], af[mt], acc[mt][nt]);   // D = C^T
    __builtin_amdgcn_s_setprio(0);
    cur = (cur == 2) ? 0 : cur + 1;
  }

  #pragma unroll
  for (int mt = 0; mt < 2; ++mt) {
    const int m = m0 + wave * 32 + mt * 16 + cl;
    #pragma unroll
    for (int nt = 0; nt < 4; ++nt) {
      const int n = n0 + nt * 16 + quad * 4;
      const float4 bv = *(const float4*)(bias + n);
      float4 o;
      o.x = acc[mt][nt][0] + bv.x; o.y = acc[mt][nt][1] + bv.y;
      o.z = acc[mt][nt][2] + bv.z; o.w = acc[mt][nt][3] + bv.w;
      *(float4*)&OutF[(size_t)m * 1024 + n] = o;
    }
  }
}

// ---------------------------------------------------------------------------
// Flash attention (unchanged R16): unpaired q-groups (1024 blocks, wave owns
// group G=4p'+w, all 4 waves scan chunks 0..p', big-work-first), triple-
// buffered K/V staging + counted vmcnt(4), inline-asm v_exp_f32 softmax.
// LDS 53248B -> 3 blocks/CU.
// ---------------------------------------------------------------------------
__global__ __launch_bounds__(256) void attn_mfma(const unsigned short* __restrict__ Qb,
                                                 const unsigned short* __restrict__ Kb,
                                                 const unsigned short* __restrict__ Vt,
                                                 unsigned short* __restrict__ CTX)
{
  __shared__ unsigned short Ksm[3][64 * 64];
  __shared__ unsigned short Vsm[3][64 * 64];
  __shared__ unsigned short Psm[4][16 * 40];

  const int tid  = threadIdx.x;
  const int wave = tid >> 6, lane = tid & 63, quad = lane >> 4, cl = lane & 15;

  const int L  = blockIdx.x;
  const int bh = 4 * (L & 7) + ((L >> 3) & 3);    // XCD-affine: 4 bh per XCD
  const int b  = bh >> 4, h = bh & 15;
  const int pp = 31 - (L >> 5);                   // 0..31, big-work-first
  const int G  = pp * 4 + wave;                   // q-group 0..127
  const int qb = G * 16;
  const size_t base = (size_t)bh * (2048 * 64);

  bf16x8 qf[2];
  #pragma unroll
  for (int dk = 0; dk < 2; ++dk)
    qf[dk] = *(const bf16x8*)(Qb + base + (size_t)(qb + cl) * 64 + dk * 32 + quad * 8);

  f32x4 oacc[4];
  #pragma unroll
  for (int dt = 0; dt < 4; ++dt)
    #pragma unroll
    for (int r = 0; r < 4; ++r) oacc[dt][r] = 0.f;
  float lr[4] = {};

  bf16x8 ones;
  #pragma unroll
  for (int k = 0; k < 8; ++k) ones[k] = (short)0x3F80;

  const int lrow  = lane >> 3;
  const int lslot = (lane & 7) ^ lrow;
  const int nch = pp + 1;                          // 1..32 chunks

  auto stageKV = [&](int j64, int buf) {
    #pragma unroll
    for (int ii = 0; ii < 2; ++ii) {
      const int r0 = wave * 16 + ii * 8;
      GLDS16(Kb + base + (size_t)(j64 + r0 + lrow) * 64 + lslot * 8, &Ksm[buf][r0 * 64]);
      GLDS16(Vt + base + (size_t)(r0 + lrow) * 2048 + j64 + lslot * 8, &Vsm[buf][r0 * 64]);
    }
  };

  // Prologue: chunk 0 and chunk 1 (chunk-1 rows always exist in the 2048-row
  // arrays; staged-but-unused for nch==1, drained by final ASYNC_BAR(0)).
  stageKV(0, 0);
  stageKV(64, 1);
  int cur = 0;
  #pragma unroll 1
  for (int ch = 0; ch < nch; ++ch) {
    if (ch + 2 < nch) {
      ASYNC_BAR(4);                              // drain stage(ch); keep stage(ch+1)
      const int bnx = (cur == 0) ? 2 : cur - 1;  // (cur+2)%3
      stageKV((ch + 2) * 64, bnx);
    } else if (ch + 1 < nch) {
      ASYNC_BAR(4);
    } else {
      ASYNC_BAR(0);
    }

    const unsigned short* Kc = Ksm[cur];
    const unsigned short* Vc = Vsm[cur];

    const int j64 = ch * 64;
    #pragma unroll
    for (int jli = 0; jli < 2; ++jli) {
      const int jg0 = j64 + jli * 32;
      if (jg0 > qb + 15) continue;                 // waves 0,1 skip hi half of last chunk
      const int jl = jli * 32;

      bf16x8 kf[2][2];
      #pragma unroll
      for (int jf = 0; jf < 2; ++jf)
        #pragma unroll
        for (int dk = 0; dk < 2; ++dk) {
          const int jrow = jl + jf * 16 + cl;
          const int slot = (dk * 4 + quad) ^ (cl & 7);
          kf[jf][dk] = *(const bf16x8*)&Kc[jrow * 64 + slot * 8];
        }

      f32x4 st[2];
      __builtin_amdgcn_s_setprio(1);
      #pragma unroll
      for (int jf = 0; jf < 2; ++jf) {
        f32x4 z;
        #pragma unroll
        for (int r = 0; r < 4; ++r) z[r] = 0.f;
        z = MFMA16(kf[jf][0], qf[0], z);
        st[jf] = MFMA16(kf[jf][1], qf[1], z);
      }
      __builtin_amdgcn_s_setprio(0);

      const bool diag = (jg0 + 32 > qb);
      #pragma unroll
      for (int jf = 0; jf < 2; ++jf) {
        float pv[4];
        if (diag) {
          const int qg = qb + cl;
          #pragma unroll
          for (int r = 0; r < 4; ++r) {
            const int jg = jg0 + jf * 16 + quad * 4 + r;
            pv[r] = (jg <= qg) ? EXP2F(st[jf][r]) : 0.f;
          }
        } else {
          #pragma unroll
          for (int r = 0; r < 4; ++r) pv[r] = EXP2F(st[jf][r]);
        }
        uint2 w;
        w.x = pk2bf(pv[0], pv[1]);
        w.y = pk2bf(pv[2], pv[3]);
        *(uint2*)&Psm[wave][cl * 40 + jf * 16 + quad * 4] = w;
      }

      bf16x8 vf[4];
      #pragma unroll
      for (int dt = 0; dt < 4; ++dt) {
        const int d = dt * 16 + cl;
        const int slot = ((jl >> 3) + quad) ^ (cl & 7);
        vf[dt] = *(const bf16x8*)&Vc[d * 64 + slot * 8];
      }

      __builtin_amdgcn_s_setprio(1);
      {
        const bf16x8 pf = *(const bf16x8*)&Psm[wave][cl * 40 + quad * 8];
        f32x4 z;
        #pragma unroll
        for (int r = 0; r < 4; ++r) z[r] = 0.f;
        const f32x4 ls = MFMA16(pf, ones, z);
        #pragma unroll
        for (int r = 0; r < 4; ++r) lr[r] += ls[r];
        #pragma unroll
        for (int dt = 0; dt < 4; ++dt)
          oacc[dt] = MFMA16(pf, vf[dt], oacc[dt]);
      }
      __builtin_amdgcn_s_setprio(0);
    }
    cur = (cur == 2) ? 0 : cur + 1;
  }

  {
    float inv[4];
    #pragma unroll
    for (int r = 0; r < 4; ++r) inv[r] = 1.f / lr[r];
    #pragma unroll
    for (int dt = 0; dt < 4; ++dt)
      #pragma unroll
      for (int r = 0; r < 4; ++r)
        CTX[(size_t)(b * 2048 + qb + quad * 4 + r) * 1024 +
            h * 64 + dt * 16 + cl] = f2bf(oacc[dt][r] * inv[r]);
  }
}

// ---------------------------------------------------------------------------
extern "C" void kernel_launch(void* const* d_in, const int* in_sizes, int n_in,
                              void* d_out, int out_size, void* d_ws, size_t ws_size,
                              hipStream_t stream)
{
  const float* x    = (const float*)d_in[0];
  const float* Wqkv = (const float*)d_in[1];
  const float* Wout = (const float*)d_in[2];
  const float* bout = (const float*)d_in[3];
  float* out = (float*)d_out;

  char* ws = (char*)d_ws;
  unsigned short* xb  = (unsigned short*)(ws);
  unsigned short* wqb = (unsigned short*)(ws + 8388608);
  unsigned short* wob = (unsigned short*)(ws + 14680064);
  unsigned short* Qb  = (unsigned short*)(ws + 16777216);
  unsigned short* Kb  = (unsigned short*)(ws + 25165824);
  unsigned short* Vt  = (unsigned short*)(ws + 33554432);
  unsigned short* CTX = (unsigned short*)(ws + 41943040);

  cast_bf16<<<dim3(8192), dim3(256), 0, stream>>>(x, Wqkv, Wout, xb, wqb, wob);

  // QKV projection: M=4096, N=3072, K=1024 -- 256^2 tile, 192 blocks
  gemm_qkv<<<dim3(192), dim3(512), 0, stream>>>(xb, wqb, Qb, Kb, Vt);

  // Flash attention: 1024 blocks (32 bh x 32 p'), 4 waves each, 1 group/wave
  attn_mfma<<<dim3(1024), dim3(256), 0, stream>>>(Qb, Kb, Vt, CTX);

  // Output projection: M=4096, N=1024, K=1024, + bias -- 128x64 tiles,
  // 512 blocks = 2 blocks/CU (gemm_bt<0> had 256 = 1/CU, ~150 TF)
  gemm_out<<<dim3(16, 32), dim3(256), 0, stream>>>(CTX, wob, bout, out);
}

// Round 8
// 185.276 us; speedup vs baseline: 1.0275x; 1.0275x over previous
//
#include <hip/hip_runtime.h>
#include <cstdint>
#include <cstddef>

// MultiHeadAttention R18:
//   gemm_qkv unchanged (256x256 8-wave phase-split, 3-bit XOR swizzle).
//   out-proj REVERTED to gemm_bt<0>-style 128^2 kernel (gemm_out at 2
//   blocks/CU measured ~2-3us worse across R5-R7).
//   attn_mfma: KVBLK 64 -> 128. Evidence: attn pinned 50.6-52.0us across
//   SIX variants (2/3/4 blk/CU, paired/unpaired, dbuf/tribuf, counted/full
//   drains). All variants share: blocks co-resident from t=0, longest block
//   = 32 chunk-rounds -> 1.61us/round invariant. Countable work is only
//   ~0.7us/round -> ~0.8us/round is per-round sync cost (vmcnt(0)+barrier
//   convergence + chain restart). Fix: HALVE the rounds. Each round covers
//   128 j as TWO 64-j sub-chunks with byte-identical staging/layout/swizzle,
//   ONE vmcnt(0)+barrier per round, dist-1 dbuf. 16 rounds max.
//   LDS 70656B -> 2 blocks/CU (occupancy proven irrelevant R12-R17).
//   Chunk/jli/arithmetic order unchanged -> bitwise-identical output.
// ws layout (bytes):
//   xb @0 [4096][1024] bf16 | wqb @8388608 [3072][1024] | wob @14680064 [1024][1024]
//   Qb @16777216, Kb @25165824: [2][16][2048][64] bf16 (Qb = Q*log2e)
//   Vt @33554432: [2][16][64][2048] bf16 (transposed)
//   CTX @41943040 [4096][1024] bf16
// MFMA 16x16x32_bf16 frags: A[m=lane&15][k=quad*8+i], B[n=lane&15][k=quad*8+i],
// C/D[row=quad*4+reg][col=lane&15]. Swapped operands -> D = C^T.

typedef __attribute__((ext_vector_type(8))) short bf16x8;
typedef __attribute__((ext_vector_type(4))) float f32x4;

#define LOG2E 1.44269504f

#define MFMA16(a, b, c) __builtin_amdgcn_mfma_f32_16x16x32_bf16((a), (b), (c), 0, 0, 0)

#define GLDS16(g, s)                                                        \
  __builtin_amdgcn_global_load_lds(                                         \
      (const __attribute__((address_space(1))) void*)(g),                   \
      (__attribute__((address_space(3))) void*)(s), 16, 0, 0)

// Manual barrier: wait until <= N vector-memory ops outstanding, then barrier.
// ONLY valid when the loop's vmem traffic is exclusively the staged GLDS.
#define ASYNC_BAR(N) asm volatile("s_waitcnt vmcnt(" #N ")\n\ts_barrier" ::: "memory")
#define BAR() asm volatile("s_barrier" ::: "memory")

// Native 2^x: v_exp_f32 (gfx950 VOP1). Input already in log2 domain.
static __device__ __forceinline__ float exp2_hw(float x) {
  float r;
  asm("v_exp_f32 %0, %1" : "=v"(r) : "v"(x));
  return r;
}
#define EXP2F(x) exp2_hw(x)

static __device__ __forceinline__ unsigned short f2bf(float f) {  // RNE
  unsigned int u = __builtin_bit_cast(unsigned int, f);
  u += 0x7FFFu + ((u >> 16) & 1u);
  return (unsigned short)(u >> 16);
}

// pack two fp32 -> two bf16 (round-nearest) in one u32: 2 add + 1 perm
static __device__ __forceinline__ unsigned int pk2bf(float a, float b) {
  const unsigned int ua = __builtin_bit_cast(unsigned int, a) + 0x8000u;
  const unsigned int ub = __builtin_bit_cast(unsigned int, b) + 0x8000u;
  return __builtin_amdgcn_perm(ub, ua, 0x07060302);
}

// ---------------------------------------------------------------------------
__global__ __launch_bounds__(256) void cast_bf16(const float* __restrict__ x,
                                                 const float* __restrict__ wq,
                                                 const float* __restrict__ wo,
                                                 unsigned short* __restrict__ xb,
                                                 unsigned short* __restrict__ wqb,
                                                 unsigned short* __restrict__ wob)
{
  const int id = blockIdx.x * 256 + threadIdx.x;
  const float* src;
  unsigned short* dst;
  int off;
  if (id < 1048576)               { src = x;  dst = xb;  off = id; }
  else if (id < 1048576 + 786432) { src = wq; dst = wqb; off = id - 1048576; }
  else                            { src = wo; dst = wob; off = id - (1048576 + 786432); }
  float4 v = ((const float4*)src)[off];
  ushort4 o;
  o.x = f2bf(v.x); o.y = f2bf(v.y); o.z = f2bf(v.z); o.w = f2bf(v.w);
  ((ushort4*)dst)[off] = o;
}

// ---------------------------------------------------------------------------
// QKV GEMM (unchanged R12): 256x256 tile, BK=64, 512 threads = 8 waves
// (2M x 4N), per-wave 128x64 output (acc[8][4] of 16x16 frags).
// LDS 128 KiB: 2 buffers x (A 256x64 | B 256x64) bf16, rows of 128B split
// into 8x16B slots, phys_slot = logical_slot ^ (row & 7)   [FULL 3-bit XOR].
// 4 phases per K-tile, 16 MFMA each; ONE vmcnt(4) per K-tile.
// ---------------------------------------------------------------------------
#define MMAC(AF, BF, MS, NS)                                                       \
  do {                                                                             \
    __builtin_amdgcn_s_setprio(1);                                                 \
    if (swapped) {                                                                 \
      _Pragma("unroll")                                                            \
      for (int mt = 0; mt < 4; ++mt)                                               \
        _Pragma("unroll")                                                          \
        for (int nt = 0; nt < 2; ++nt) {                                           \
          acc[(MS)*4+mt][(NS)*2+nt] = MFMA16(BF[nt][0], AF[mt][0], acc[(MS)*4+mt][(NS)*2+nt]); \
          acc[(MS)*4+mt][(NS)*2+nt] = MFMA16(BF[nt][1], AF[mt][1], acc[(MS)*4+mt][(NS)*2+nt]); \
        }                                                                          \
    } else {                                                                       \
      _Pragma("unroll")                                                            \
      for (int mt = 0; mt < 4; ++mt)                                               \
        _Pragma("unroll")                                                          \
        for (int nt = 0; nt < 2; ++nt) {                                           \
          acc[(MS)*4+mt][(NS)*2+nt] = MFMA16(AF[mt][0], BF[nt][0], acc[(MS)*4+mt][(NS)*2+nt]); \
          acc[(MS)*4+mt][(NS)*2+nt] = MFMA16(AF[mt][1], BF[nt][1], acc[(MS)*4+mt][(NS)*2+nt]); \
        }                                                                          \
    }                                                                              \
    __builtin_amdgcn_s_setprio(0);                                                 \
  } while (0)

__global__ __launch_bounds__(512, 2) void gemm_qkv(const unsigned short* __restrict__ A,
                                                   const unsigned short* __restrict__ B,
                                                   unsigned short* __restrict__ Qb,
                                                   unsigned short* __restrict__ Kb,
                                                   unsigned short* __restrict__ Vt)
{
  // shorts: buf b: A @ b*32768 (256 rows x 64), B @ b*32768+16384. 128 KiB.
  __shared__ unsigned short pool[65536];

  const int tid  = threadIdx.x;
  const int wave = tid >> 6, lane = tid & 63, quad = lane >> 4, cl = lane & 15;
  const int wm = wave >> 2, wn = wave & 3;

  // Bijective XCD chunking: 192 blocks, 24/XCD covering a 4(mb) x 6(nb) chunk.
  const int bid = blockIdx.x;
  const int xcd = bid & 7, j = bid >> 3;
  const int mb = (xcd >> 1) * 4 + j / 6;
  const int nb = (xcd & 1) * 6 + j % 6;
  const int m0 = mb * 256, n0 = nb * 256;
  const int part = nb >> 2;                 // 0=Q 1=K 2=V
  const bool swapped = (part < 2);

  // --- staging: per GLDS16, wave covers 8 rows x 128B linearly.
  // lane l -> row r0+(l>>3), phys slot l&7. Pre-swizzled global source:
  // logical slot = phys ^ (row&7) = (l&7) ^ (l>>3)   [r0 is a multiple of 8]
  const int lrow = lane >> 3;
  const int sg   = (lane & 7) ^ lrow;

  auto stageA = [&](int h0, int buf, int k0) {
    #pragma unroll
    for (int ii = 0; ii < 2; ++ii) {
      const int r0 = h0 + wave * 16 + ii * 8;
      GLDS16(A + (size_t)(m0 + r0 + lrow) * 1024 + k0 + sg * 8,
             &pool[buf * 32768 + r0 * 64]);
    }
  };
  auto stageB = [&](int h0, int buf, int k0) {
    #pragma unroll
    for (int ii = 0; ii < 2; ++ii) {
      const int r0 = h0 + wave * 16 + ii * 8;
      GLDS16(B + (size_t)(n0 + r0 + lrow) * 1024 + k0 + sg * 8,
             &pool[buf * 32768 + 16384 + r0 * 64]);
    }
  };

  // --- fragment reads: row = 16-aligned base + cl -> row&7 == cl&7.
  // logical k-chunk (kk*4+quad) lives at phys slot (kk*4+quad) ^ (cl&7).
  const int rswz = cl & 7;
  auto loadA = [&](bf16x8 (&af)[4][2], int msub, int b) {
    const unsigned short* base = &pool[b * 32768];
    #pragma unroll
    for (int mt = 0; mt < 4; ++mt) {
      const int row = wm * 128 + msub * 64 + mt * 16 + cl;
      #pragma unroll
      for (int kk = 0; kk < 2; ++kk)
        af[mt][kk] = *(const bf16x8*)&base[row * 64 + ((kk * 4 + quad) ^ rswz) * 8];
    }
  };
  auto loadB = [&](bf16x8 (&bf)[2][2], int nsub, int b) {
    const unsigned short* base = &pool[b * 32768 + 16384];
    #pragma unroll
    for (int nt = 0; nt < 2; ++nt) {
      const int row = wn * 64 + nsub * 32 + nt * 16 + cl;
      #pragma unroll
      for (int kk = 0; kk < 2; ++kk)
        bf[nt][kk] = *(const bf16x8*)&base[row * 64 + ((kk * 4 + quad) ^ rswz) * 8];
    }
  };

  f32x4 acc[8][4];
  #pragma unroll
  for (int i = 0; i < 8; ++i)
    #pragma unroll
    for (int jj = 0; jj < 4; ++jj)
      #pragma unroll
      for (int r = 0; r < 4; ++r) acc[i][jj][r] = 0.f;

  // Prologue: all 4 half-tiles of tile0, then lo halves of tile1 (12 loads).
  stageB(0,   0, 0);
  stageA(0,   0, 0);
  stageB(128, 0, 0);
  stageA(128, 0, 0);
  stageB(0,   1, 64);
  stageA(0,   1, 64);

  #pragma unroll 1
  for (int t = 0; t < 16; ++t) {
    const int b = t & 1, bn = b ^ 1;
    const int kc  = (t + 1) * 64;
    const int kc2 = (t + 2) * 64;

    bf16x8 af[4][2], bfA[2][2], bfB[2][2];

    // P0: quadrant (0,0). vmcnt(4): guarantees all 4 halves of tile t
    // (newest needed = A-hi(t) @ (t-1)-P1; newer in flight = B-lo/A-lo(t+1)).
    if (t < 15) { ASYNC_BAR(4); } else { ASYNC_BAR(0); }
    loadA(af, 0, b);
    loadB(bfA, 0, b);
    if (t < 15) stageB(128, bn, kc);       // B-hi(t+1)
    MMAC(af, bfA, 0, 0);

    // P1: quadrant (0,1). No barrier needed: reads tile-t B (published at P0),
    // GLDS writes buffer bn (not being read).
    loadB(bfB, 1, b);
    if (t < 15) stageA(128, bn, kc);       // A-hi(t+1)
    MMAC(af, bfB, 0, 1);

    // P2: quadrant (1,1). Barrier: B-lo(t+2) overwrites B-lo(b) whose last
    // reads were P1 (other waves).
    BAR();
    loadA(af, 1, b);
    if (t < 14) stageB(0, b, kc2);         // B-lo(t+2)
    MMAC(af, bfB, 1, 1);

    // P3: quadrant (1,0), reuses bfA regs. Barrier: A-lo(t+2) overwrites
    // A-lo(b) whose last reads were P2 (wm=0 waves).
    BAR();
    if (t < 14) stageA(0, b, kc2);         // A-lo(t+2)
    MMAC(af, bfA, 1, 0);
  }
  // ASYNC_BAR(0) at t=15-P0 drained all staging: no GLDS in flight here.

  const int bb = m0 >> 11, ss = m0 & 2047;
  if (part < 2) {
    // Q/K (swapped: D=C^T): lane holds 4 consecutive d for one s -> ushort4
    unsigned short* dst = (part == 0) ? Qb : Kb;
    const float sc2 = (part == 0) ? LOG2E : 1.0f;
    const int npb = (n0 & 1023) + wn * 64;
    #pragma unroll
    for (int mt = 0; mt < 8; ++mt) {
      const int m = ss + wm * 128 + mt * 16 + cl;
      #pragma unroll
      for (int nt = 0; nt < 4; ++nt) {
        const int np = npb + nt * 16 + quad * 4;
        const int hh = np >> 6, d0 = np & 63;
        ushort4 pk;
        pk.x = f2bf(acc[mt][nt][0] * sc2);
        pk.y = f2bf(acc[mt][nt][1] * sc2);
        pk.z = f2bf(acc[mt][nt][2] * sc2);
        pk.w = f2bf(acc[mt][nt][3] * sc2);
        *(ushort4*)&dst[((size_t)(bb * 16 + hh) * 2048 + m) * 64 + d0] = pk;
      }
    }
  } else {
    // V (normal orientation): transpose through LDS (reuse pool),
    // trans[128][264] shorts per round; 2 rounds (wn pairs).
    unsigned short* trans = pool;
    #pragma unroll 1
    for (int r = 0; r < 2; ++r) {
      __syncthreads();
      if ((wn >> 1) == r) {
        #pragma unroll
        for (int mt = 0; mt < 8; ++mt) {
          const int s_l = wm * 128 + mt * 16 + quad * 4;
          #pragma unroll
          for (int nt = 0; nt < 4; ++nt) {
            const int n_l = (wn & 1) * 64 + nt * 16 + cl;
            ushort4 pk;
            pk.x = f2bf(acc[mt][nt][0]); pk.y = f2bf(acc[mt][nt][1]);
            pk.z = f2bf(acc[mt][nt][2]); pk.w = f2bf(acc[mt][nt][3]);
            *(ushort4*)&trans[n_l * 264 + s_l] = pk;
          }
        }
      }
      __syncthreads();
      const int row = tid >> 2, q4 = tid & 3;
      const int nv = (n0 & 1023) + r * 128 + row;
      const int hh = nv >> 6, d = nv & 63;
      unsigned short* drow = Vt + ((size_t)(bb * 16 + hh) * 64 + d) * 2048 + ss + q4 * 64;
      #pragma unroll
      for (int i = 0; i < 8; ++i)
        *(bf16x8*)(drow + i * 8) = *(const bf16x8*)&trans[row * 264 + q4 * 64 + i * 8];
    }
  }
}

// ---------------------------------------------------------------------------
// Out-projection (reverted to proven R16 gemm_bt<0> structure): 128^2 tile,
// 4 waves, TRIPLE-buffered K-loop, counted vmcnt(4), grid 8x32 = 256 blocks.
// ---------------------------------------------------------------------------
__global__ __launch_bounds__(256) void gemm_obt(const unsigned short* __restrict__ A,
                                                const unsigned short* __restrict__ B,
                                                const float* __restrict__ bias,
                                                float* __restrict__ OutF)
{
  __shared__ unsigned short pool[24576];   // 3 stages x (A 4096 | B 4096) shorts

  const int tid  = threadIdx.x;
  const int wave = tid >> 6, lane = tid & 63, quad = lane >> 4, cl = lane & 15;
  const int wm = wave >> 1, wn = wave & 1;
  const int m0 = blockIdx.y * 128, n0 = blockIdx.x * 128;
  const int sr = lane >> 2, sc = lane & 3;

  f32x4 acc[4][4];
  #pragma unroll
  for (int i = 0; i < 4; ++i)
    #pragma unroll
    for (int j = 0; j < 4; ++j)
      #pragma unroll
      for (int r = 0; r < 4; ++r) acc[i][j][r] = 0.f;

  const int scs = (sc ^ ((sr >> 1) & 3)) * 8;
  const int rchunk = (quad ^ ((cl >> 1) & 3)) * 8;

  auto stage = [&](int k0, int buf) {
    unsigned short* As = pool + buf * 8192;
    unsigned short* Bs = As + 4096;
    #pragma unroll
    for (int ii = 0; ii < 2; ++ii) {
      const int r = wave * 32 + ii * 16 + sr;
      GLDS16(A + (size_t)(m0 + r) * 1024 + k0 + scs, &As[(wave * 32 + ii * 16) * 32]);
      GLDS16(B + (size_t)(n0 + r) * 1024 + k0 + scs, &Bs[(wave * 32 + ii * 16) * 32]);
    }
  };

  stage(0, 0);
  stage(32, 1);
  int cur = 0;
  #pragma unroll 1
  for (int it = 0; it < 32; ++it) {
    if (it + 2 < 32) {
      ASYNC_BAR(4);                              // drain stage(it); keep stage(it+1)
      const int bnx = (cur == 0) ? 2 : cur - 1;  // (cur+2)%3
      stage((it + 2) * 32, bnx);
    } else if (it + 1 < 32) {
      ASYNC_BAR(4);
    } else {
      ASYNC_BAR(0);
    }

    const unsigned short* As = pool + cur * 8192;
    const unsigned short* Bs = As + 4096;
    bf16x8 af[4], bfr[4];
    #pragma unroll
    for (int mt = 0; mt < 4; ++mt)
      af[mt] = *(const bf16x8*)&As[(wm * 64 + mt * 16 + cl) * 32 + rchunk];
    #pragma unroll
    for (int nt = 0; nt < 4; ++nt)
      bfr[nt] = *(const bf16x8*)&Bs[(wn * 64 + nt * 16 + cl) * 32 + rchunk];

    __builtin_amdgcn_s_setprio(1);
    #pragma unroll
    for (int mt = 0; mt < 4; ++mt)
      #pragma unroll
      for (int nt = 0; nt < 4; ++nt)
        acc[mt][nt] = MFMA16(bfr[nt], af[mt], acc[mt][nt]);   // D = C^T
    __builtin_amdgcn_s_setprio(0);
    cur = (cur == 2) ? 0 : cur + 1;
  }

  #pragma unroll
  for (int mt = 0; mt < 4; ++mt) {
    const int m = m0 + wm * 64 + mt * 16 + cl;
    #pragma unroll
    for (int nt = 0; nt < 4; ++nt) {
      const int n = n0 + wn * 64 + nt * 16 + quad * 4;
      const float4 bv = *(const float4*)(bias + n);
      float4 o;
      o.x = acc[mt][nt][0] + bv.x; o.y = acc[mt][nt][1] + bv.y;
      o.z = acc[mt][nt][2] + bv.z; o.w = acc[mt][nt][3] + bv.w;
      *(float4*)&OutF[(size_t)m * 1024 + n] = o;
    }
  }
}

// ---------------------------------------------------------------------------
// Flash attention R18: unpaired q-groups (1024 blocks, wave owns group
// G=4p'+w, all 4 waves scan the same chunk range, big-work-first), KVBLK=128:
// each ROUND covers two 64-j sub-chunks (staging/layout/swizzle byte-
// identical to the 64-j version, indexed by sub). ONE vmcnt(0)+barrier per
// round, dist-1 round double-buffer. Max 16 rounds (was 32 barrier-rounds).
// LDS: Ksm 32KB + Vsm 32KB + Psm 5KB = 70656B -> 2 blocks/CU.
// v_exp_f32 asm softmax. Chunk/jli/arith order unchanged -> bitwise output.
// ---------------------------------------------------------------------------
__global__ __launch_bounds__(256) void attn_mfma(const unsigned short* __restrict__ Qb,
                                                 const unsigned short* __restrict__ Kb,
                                                 const unsigned short* __restrict__ Vt,
                                                 unsigned short* __restrict__ CTX)
{
  __shared__ unsigned short Ksm[2][2][64 * 64];   // [round buf][sub][64 rows x 128B]
  __shared__ unsigned short Vsm[2][2][64 * 64];
  __shared__ unsigned short Psm[4][16 * 40];

  const int tid  = threadIdx.x;
  const int wave = tid >> 6, lane = tid & 63, quad = lane >> 4, cl = lane & 15;

  const int L  = blockIdx.x;
  const int bh = 4 * (L & 7) + ((L >> 3) & 3);    // XCD-affine: 4 bh per XCD
  const int b  = bh >> 4, h = bh & 15;
  const int pp = 31 - (L >> 5);                   // 0..31, big-work-first
  const int G  = pp * 4 + wave;                   // q-group 0..127
  const int qb = G * 16;
  const size_t base = (size_t)bh * (2048 * 64);

  bf16x8 qf[2];
  #pragma unroll
  for (int dk = 0; dk < 2; ++dk)
    qf[dk] = *(const bf16x8*)(Qb + base + (size_t)(qb + cl) * 64 + dk * 32 + quad * 8);

  f32x4 oacc[4];
  #pragma unroll
  for (int dt = 0; dt < 4; ++dt)
    #pragma unroll
    for (int r = 0; r < 4; ++r) oacc[dt][r] = 0.f;
  float lr[4] = {};

  bf16x8 ones;
  #pragma unroll
  for (int k = 0; k < 8; ++k) ones[k] = (short)0x3F80;

  const int lrow  = lane >> 3;
  const int lslot = (lane & 7) ^ lrow;
  const int nch = pp + 1;                          // 64-chunks: 1..32
  const int nrd = (nch + 1) >> 1;                  // 128-rounds: 1..16

  // Stage one 64-j sub-chunk (byte-identical layout to the 64-j version).
  auto stageKV = [&](int ch, int buf, int sub) {
    const int j64 = ch * 64;
    #pragma unroll
    for (int ii = 0; ii < 2; ++ii) {
      const int r0 = wave * 16 + ii * 8;
      GLDS16(Kb + base + (size_t)(j64 + r0 + lrow) * 64 + lslot * 8,
             &Ksm[buf][sub][r0 * 64]);
      GLDS16(Vt + base + (size_t)(r0 + lrow) * 2048 + j64 + lslot * 8,
             &Vsm[buf][sub][r0 * 64]);
    }
  };

  // Prologue: round 0 = chunks 0,1 (chunk 1 always within the 2048-row
  // arrays; if unused (pp=0) it is drained by the round-0 ASYNC_BAR(0)).
  stageKV(0, 0, 0);
  stageKV(1, 0, 1);

  #pragma unroll 1
  for (int t = 0; t < nrd; ++t) {
    // Drain round t's 8 GLDS (issued a full round ago; K/V L2-resident) and
    // sync. Barrier also proves all waves are past round t-1's reads of
    // buf[(t+1)&1] -> safe to overwrite.
    ASYNC_BAR(0);
    if (t + 1 < nrd) {
      stageKV(2 * t + 2, (t + 1) & 1, 0);
      stageKV(2 * t + 3, (t + 1) & 1, 1);
    }

    #pragma unroll
    for (int cs = 0; cs < 2; ++cs) {
      const int ch = 2 * t + cs;
      const unsigned short* Kc = Ksm[t & 1][cs];
      const unsigned short* Vc = Vsm[t & 1][cs];
      const int j64c = ch * 64;

      #pragma unroll
      for (int jli = 0; jli < 2; ++jli) {
        const int jg0 = j64c + jli * 32;
        if (jg0 > qb + 15) continue;               // causal skip (covers odd-nch tail)
        const int jl = jli * 32;

        bf16x8 kf[2][2];
        #pragma unroll
        for (int jf = 0; jf < 2; ++jf)
          #pragma unroll
          for (int dk = 0; dk < 2; ++dk) {
            const int jrow = jl + jf * 16 + cl;
            const int slot = (dk * 4 + quad) ^ (cl & 7);
            kf[jf][dk] = *(const bf16x8*)&Kc[jrow * 64 + slot * 8];
          }

        f32x4 st[2];
        __builtin_amdgcn_s_setprio(1);
        #pragma unroll
        for (int jf = 0; jf < 2; ++jf) {
          f32x4 z;
          #pragma unroll
          for (int r = 0; r < 4; ++r) z[r] = 0.f;
          z = MFMA16(kf[jf][0], qf[0], z);
          st[jf] = MFMA16(kf[jf][1], qf[1], z);
        }
        __builtin_amdgcn_s_setprio(0);

        const bool diag = (jg0 + 32 > qb);
        #pragma unroll
        for (int jf = 0; jf < 2; ++jf) {
          float pv[4];
          if (diag) {
            const int qg = qb + cl;
            #pragma unroll
            for (int r = 0; r < 4; ++r) {
              const int jg = jg0 + jf * 16 + quad * 4 + r;
              pv[r] = (jg <= qg) ? EXP2F(st[jf][r]) : 0.f;
            }
          } else {
            #pragma unroll
            for (int r = 0; r < 4; ++r) pv[r] = EXP2F(st[jf][r]);
          }
          uint2 w;
          w.x = pk2bf(pv[0], pv[1]);
          w.y = pk2bf(pv[2], pv[3]);
          *(uint2*)&Psm[wave][cl * 40 + jf * 16 + quad * 4] = w;
        }

        bf16x8 vf[4];
        #pragma unroll
        for (int dt = 0; dt < 4; ++dt) {
          const int d = dt * 16 + cl;
          const int slot = ((jl >> 3) + quad) ^ (cl & 7);
          vf[dt] = *(const bf16x8*)&Vc[d * 64 + slot * 8];
        }

        __builtin_amdgcn_s_setprio(1);
        {
          const bf16x8 pf = *(const bf16x8*)&Psm[wave][cl * 40 + quad * 8];
          f32x4 z;
          #pragma unroll
          for (int r = 0; r < 4; ++r) z[r] = 0.f;
          const f32x4 ls = MFMA16(pf, ones, z);
          #pragma unroll
          for (int r = 0; r < 4; ++r) lr[r] += ls[r];
          #pragma unroll
          for (int dt = 0; dt < 4; ++dt)
            oacc[dt] = MFMA16(pf, vf[dt], oacc[dt]);
        }
        __builtin_amdgcn_s_setprio(0);
      }
    }
  }

  {
    float inv[4];
    #pragma unroll
    for (int r = 0; r < 4; ++r) inv[r] = 1.f / lr[r];
    #pragma unroll
    for (int dt = 0; dt < 4; ++dt)
      #pragma unroll
      for (int r = 0; r < 4; ++r)
        CTX[(size_t)(b * 2048 + qb + quad * 4 + r) * 1024 +
            h * 64 + dt * 16 + cl] = f2bf(oacc[dt][r] * inv[r]);
  }
}

// ---------------------------------------------------------------------------
extern "C" void kernel_launch(void* const* d_in, const int* in_sizes, int n_in,
                              void* d_out, int out_size, void* d_ws, size_t ws_size,
                              hipStream_t stream)
{
  const float* x    = (const float*)d_in[0];
  const float* Wqkv = (const float*)d_in[1];
  const float* Wout = (const float*)d_in[2];
  const float* bout = (const float*)d_in[3];
  float* out = (float*)d_out;

  char* ws = (char*)d_ws;
  unsigned short* xb  = (unsigned short*)(ws);
  unsigned short* wqb = (unsigned short*)(ws + 8388608);
  unsigned short* wob = (unsigned short*)(ws + 14680064);
  unsigned short* Qb  = (unsigned short*)(ws + 16777216);
  unsigned short* Kb  = (unsigned short*)(ws + 25165824);
  unsigned short* Vt  = (unsigned short*)(ws + 33554432);
  unsigned short* CTX = (unsigned short*)(ws + 41943040);

  cast_bf16<<<dim3(8192), dim3(256), 0, stream>>>(x, Wqkv, Wout, xb, wqb, wob);

  // QKV projection: M=4096, N=3072, K=1024 -- 256^2 tile, 192 blocks
  gemm_qkv<<<dim3(192), dim3(512), 0, stream>>>(xb, wqb, Qb, Kb, Vt);

  // Flash attention: 1024 blocks (32 bh x 32 p'), 4 waves, KVBLK=128 rounds
  attn_mfma<<<dim3(1024), dim3(256), 0, stream>>>(Qb, Kb, Vt, CTX);

  // Output projection: M=4096, N=1024, K=1024, + bias (proven 128^2 kernel)
  gemm_obt<<<dim3(8, 32), dim3(256), 0, stream>>>(CTX, wob, bout, out);
}

// Round 11
// 184.253 us; speedup vs baseline: 1.0332x; 1.0056x over previous
//
#include <hip/hip_runtime.h>
#include <cstdint>
#include <cstddef>

// MultiHeadAttention R21 (= R19 with the host-pass compile fix; R10 failed
// because __has_builtin(__builtin_amdgcn_*) is FALSE in hipcc's HOST pass,
// so the guard #error fired "when compiling for host". Fix: gate on
// __HIP_DEVICE_COMPILE__ -- host gets an unexecuted (c) stub, device keeps
// the __has_builtin chain where it answers correctly).
//   gemm_qkv unchanged (256x256 8-wave phase-split, 3-bit XOR swizzle).
//   gemm_obt unchanged (proven 128^2 out-proj).
//   attn_mfma: Psm ELIMINATED -- P stays in registers. Evidence: per-chunk
//   wall ~3700cy is a fixed latency floor (R12 2x-work same time; R18
//   barrier-halving saved only 0.14us/round), and SQ_LDS_BANK_CONFLICT =
//   1,597,440 in EVERY variant incl. R14 (no K/V staging) -> all conflicts
//   + a ~240cy write->read chain live in the Psm round trip. Fix: swapped-
//   QK output st[jf][r] = P[q=cl][jf*16+quad*4+r] is ALREADY the K=16 MFMA
//   A-fragment layout (A[m=cl][k=quad*4+i]). PV + row-sum now use
//   v_mfma_f32_16x16x16_bf16 (two chained K=16 per j-32-block), pf =
//   bitcast of the pk2bf words -- zero data movement. V frags read as
//   ds_read_b64 at quad*4 granule (same staged bytes, same XOR swizzle).
//   Numerics: K=32 sum split into two K=16 steps (~1ulp f32 wiggle).
// ws layout (bytes):
//   xb @0 [4096][1024] bf16 | wqb @8388608 [3072][1024] | wob @14680064 [1024][1024]
//   Qb @16777216, Kb @25165824: [2][16][2048][64] bf16 (Qb = Q*log2e)
//   Vt @33554432: [2][16][64][2048] bf16 (transposed)
//   CTX @41943040 [4096][1024] bf16
// MFMA 16x16x32_bf16 frags: A[m=lane&15][k=quad*8+i], B[n=lane&15][k=quad*8+i],
// C/D[row=quad*4+reg][col=lane&15]. 16x16x16: k=quad*4+i, same C/D.
// Swapped operands -> D = C^T.

typedef __attribute__((ext_vector_type(8))) short bf16x8;
typedef __attribute__((ext_vector_type(4))) short bf16x4;
typedef __attribute__((ext_vector_type(4))) float f32x4;

#define LOG2E 1.44269504f

#define MFMA16(a, b, c) __builtin_amdgcn_mfma_f32_16x16x32_bf16((a), (b), (c), 0, 0, 0)

// K=16 bf16 MFMA: guard must only run in the DEVICE pass -- __has_builtin
// returns false for amdgcn builtins during hipcc's host pass (R10 lesson).
#if defined(__HIP_DEVICE_COMPILE__)
  #if __has_builtin(__builtin_amdgcn_mfma_f32_16x16x16bf16_1k)
    #define MFMAK16(a, b, c) __builtin_amdgcn_mfma_f32_16x16x16bf16_1k((a), (b), (c), 0, 0, 0)
  #elif __has_builtin(__builtin_amdgcn_mfma_f32_16x16x16_bf16)
    #define MFMAK16(a, b, c) __builtin_amdgcn_mfma_f32_16x16x16_bf16((a), (b), (c), 0, 0, 0)
  #else
    #error "no 16x16x16 bf16 MFMA builtin on device"
  #endif
#else
  #define MFMAK16(a, b, c) (c)   // host pass: parsed, never executed
#endif

#define GLDS16(g, s)                                                        \
  __builtin_amdgcn_global_load_lds(                                         \
      (const __attribute__((address_space(1))) void*)(g),                   \
      (__attribute__((address_space(3))) void*)(s), 16, 0, 0)

// Manual barrier: wait until <= N vector-memory ops outstanding, then barrier.
// ONLY valid when the loop's vmem traffic is exclusively the staged GLDS.
#define ASYNC_BAR(N) asm volatile("s_waitcnt vmcnt(" #N ")\n\ts_barrier" ::: "memory")
#define BAR() asm volatile("s_barrier" ::: "memory")

// Native 2^x: v_exp_f32 (gfx950 VOP1). Input already in log2 domain.
static __device__ __forceinline__ float exp2_hw(float x) {
  float r;
  asm("v_exp_f32 %0, %1" : "=v"(r) : "v"(x));
  return r;
}
#define EXP2F(x) exp2_hw(x)

static __device__ __forceinline__ unsigned short f2bf(float f) {  // RNE
  unsigned int u = __builtin_bit_cast(unsigned int, f);
  u += 0x7FFFu + ((u >> 16) & 1u);
  return (unsigned short)(u >> 16);
}

// pack two fp32 -> two bf16 (round-nearest) in one u32: 2 add + 1 perm
static __device__ __forceinline__ unsigned int pk2bf(float a, float b) {
  const unsigned int ua = __builtin_bit_cast(unsigned int, a) + 0x8000u;
  const unsigned int ub = __builtin_bit_cast(unsigned int, b) + 0x8000u;
  return __builtin_amdgcn_perm(ub, ua, 0x07060302);
}

// ---------------------------------------------------------------------------
__global__ __launch_bounds__(256) void cast_bf16(const float* __restrict__ x,
                                                 const float* __restrict__ wq,
                                                 const float* __restrict__ wo,
                                                 unsigned short* __restrict__ xb,
                                                 unsigned short* __restrict__ wqb,
                                                 unsigned short* __restrict__ wob)
{
  const int id = blockIdx.x * 256 + threadIdx.x;
  const float* src;
  unsigned short* dst;
  int off;
  if (id < 1048576)               { src = x;  dst = xb;  off = id; }
  else if (id < 1048576 + 786432) { src = wq; dst = wqb; off = id - 1048576; }
  else                            { src = wo; dst = wob; off = id - (1048576 + 786432); }
  float4 v = ((const float4*)src)[off];
  ushort4 o;
  o.x = f2bf(v.x); o.y = f2bf(v.y); o.z = f2bf(v.z); o.w = f2bf(v.w);
  ((ushort4*)dst)[off] = o;
}

// ---------------------------------------------------------------------------
// QKV GEMM (unchanged R12): 256x256 tile, BK=64, 512 threads = 8 waves
// (2M x 4N), per-wave 128x64 output (acc[8][4] of 16x16 frags).
// LDS 128 KiB: 2 buffers x (A 256x64 | B 256x64) bf16, rows of 128B split
// into 8x16B slots, phys_slot = logical_slot ^ (row & 7)   [FULL 3-bit XOR].
// 4 phases per K-tile, 16 MFMA each; ONE vmcnt(4) per K-tile.
// ---------------------------------------------------------------------------
#define MMAC(AF, BF, MS, NS)                                                       \
  do {                                                                             \
    __builtin_amdgcn_s_setprio(1);                                                 \
    if (swapped) {                                                                 \
      _Pragma("unroll")                                                            \
      for (int mt = 0; mt < 4; ++mt)                                               \
        _Pragma("unroll")                                                          \
        for (int nt = 0; nt < 2; ++nt) {                                           \
          acc[(MS)*4+mt][(NS)*2+nt] = MFMA16(BF[nt][0], AF[mt][0], acc[(MS)*4+mt][(NS)*2+nt]); \
          acc[(MS)*4+mt][(NS)*2+nt] = MFMA16(BF[nt][1], AF[mt][1], acc[(MS)*4+mt][(NS)*2+nt]); \
        }                                                                          \
    } else {                                                                       \
      _Pragma("unroll")                                                            \
      for (int mt = 0; mt < 4; ++mt)                                               \
        _Pragma("unroll")                                                          \
        for (int nt = 0; nt < 2; ++nt) {                                           \
          acc[(MS)*4+mt][(NS)*2+nt] = MFMA16(AF[mt][0], BF[nt][0], acc[(MS)*4+mt][(NS)*2+nt]); \
          acc[(MS)*4+mt][(NS)*2+nt] = MFMA16(AF[mt][1], BF[nt][1], acc[(MS)*4+mt][(NS)*2+nt]); \
        }                                                                          \
    }                                                                              \
    __builtin_amdgcn_s_setprio(0);                                                 \
  } while (0)

__global__ __launch_bounds__(512, 2) void gemm_qkv(const unsigned short* __restrict__ A,
                                                   const unsigned short* __restrict__ B,
                                                   unsigned short* __restrict__ Qb,
                                                   unsigned short* __restrict__ Kb,
                                                   unsigned short* __restrict__ Vt)
{
  // shorts: buf b: A @ b*32768 (256 rows x 64), B @ b*32768+16384. 128 KiB.
  __shared__ unsigned short pool[65536];

  const int tid  = threadIdx.x;
  const int wave = tid >> 6, lane = tid & 63, quad = lane >> 4, cl = lane & 15;
  const int wm = wave >> 2, wn = wave & 3;

  // Bijective XCD chunking: 192 blocks, 24/XCD covering a 4(mb) x 6(nb) chunk.
  const int bid = blockIdx.x;
  const int xcd = bid & 7, j = bid >> 3;
  const int mb = (xcd >> 1) * 4 + j / 6;
  const int nb = (xcd & 1) * 6 + j % 6;
  const int m0 = mb * 256, n0 = nb * 256;
  const int part = nb >> 2;                 // 0=Q 1=K 2=V
  const bool swapped = (part < 2);

  // --- staging: per GLDS16, wave covers 8 rows x 128B linearly.
  // lane l -> row r0+(l>>3), phys slot l&7. Pre-swizzled global source:
  // logical slot = phys ^ (row&7) = (l&7) ^ (l>>3)   [r0 is a multiple of 8]
  const int lrow = lane >> 3;
  const int sg   = (lane & 7) ^ lrow;

  auto stageA = [&](int h0, int buf, int k0) {
    #pragma unroll
    for (int ii = 0; ii < 2; ++ii) {
      const int r0 = h0 + wave * 16 + ii * 8;
      GLDS16(A + (size_t)(m0 + r0 + lrow) * 1024 + k0 + sg * 8,
             &pool[buf * 32768 + r0 * 64]);
    }
  };
  auto stageB = [&](int h0, int buf, int k0) {
    #pragma unroll
    for (int ii = 0; ii < 2; ++ii) {
      const int r0 = h0 + wave * 16 + ii * 8;
      GLDS16(B + (size_t)(n0 + r0 + lrow) * 1024 + k0 + sg * 8,
             &pool[buf * 32768 + 16384 + r0 * 64]);
    }
  };

  // --- fragment reads: row = 16-aligned base + cl -> row&7 == cl&7.
  // logical k-chunk (kk*4+quad) lives at phys slot (kk*4+quad) ^ (cl&7).
  const int rswz = cl & 7;
  auto loadA = [&](bf16x8 (&af)[4][2], int msub, int b) {
    const unsigned short* base = &pool[b * 32768];
    #pragma unroll
    for (int mt = 0; mt < 4; ++mt) {
      const int row = wm * 128 + msub * 64 + mt * 16 + cl;
      #pragma unroll
      for (int kk = 0; kk < 2; ++kk)
        af[mt][kk] = *(const bf16x8*)&base[row * 64 + ((kk * 4 + quad) ^ rswz) * 8];
    }
  };
  auto loadB = [&](bf16x8 (&bf)[2][2], int nsub, int b) {
    const unsigned short* base = &pool[b * 32768 + 16384];
    #pragma unroll
    for (int nt = 0; nt < 2; ++nt) {
      const int row = wn * 64 + nsub * 32 + nt * 16 + cl;
      #pragma unroll
      for (int kk = 0; kk < 2; ++kk)
        bf[nt][kk] = *(const bf16x8*)&base[row * 64 + ((kk * 4 + quad) ^ rswz) * 8];
    }
  };

  f32x4 acc[8][4];
  #pragma unroll
  for (int i = 0; i < 8; ++i)
    #pragma unroll
    for (int jj = 0; jj < 4; ++jj)
      #pragma unroll
      for (int r = 0; r < 4; ++r) acc[i][jj][r] = 0.f;

  // Prologue: all 4 half-tiles of tile0, then lo halves of tile1 (12 loads).
  stageB(0,   0, 0);
  stageA(0,   0, 0);
  stageB(128, 0, 0);
  stageA(128, 0, 0);
  stageB(0,   1, 64);
  stageA(0,   1, 64);

  #pragma unroll 1
  for (int t = 0; t < 16; ++t) {
    const int b = t & 1, bn = b ^ 1;
    const int kc  = (t + 1) * 64;
    const int kc2 = (t + 2) * 64;

    bf16x8 af[4][2], bfA[2][2], bfB[2][2];

    // P0: quadrant (0,0). vmcnt(4): guarantees all 4 halves of tile t
    // (newest needed = A-hi(t) @ (t-1)-P1; newer in flight = B-lo/A-lo(t+1)).
    if (t < 15) { ASYNC_BAR(4); } else { ASYNC_BAR(0); }
    loadA(af, 0, b);
    loadB(bfA, 0, b);
    if (t < 15) stageB(128, bn, kc);       // B-hi(t+1)
    MMAC(af, bfA, 0, 0);

    // P1: quadrant (0,1). No barrier needed: reads tile-t B (published at P0),
    // GLDS writes buffer bn (not being read).
    loadB(bfB, 1, b);
    if (t < 15) stageA(128, bn, kc);       // A-hi(t+1)
    MMAC(af, bfB, 0, 1);

    // P2: quadrant (1,1). Barrier: B-lo(t+2) overwrites B-lo(b) whose last
    // reads were P1 (other waves).
    BAR();
    loadA(af, 1, b);
    if (t < 14) stageB(0, b, kc2);         // B-lo(t+2)
    MMAC(af, bfB, 1, 1);

    // P3: quadrant (1,0), reuses bfA regs. Barrier: A-lo(t+2) overwrites
    // A-lo(b) whose last reads were P2 (wm=0 waves).
    BAR();
    if (t < 14) stageA(0, b, kc2);         // A-lo(t+2)
    MMAC(af, bfA, 1, 0);
  }
  // ASYNC_BAR(0) at t=15-P0 drained all staging: no GLDS in flight here.

  const int bb = m0 >> 11, ss = m0 & 2047;
  if (part < 2) {
    // Q/K (swapped: D=C^T): lane holds 4 consecutive d for one s -> ushort4
    unsigned short* dst = (part == 0) ? Qb : Kb;
    const float sc2 = (part == 0) ? LOG2E : 1.0f;
    const int npb = (n0 & 1023) + wn * 64;
    #pragma unroll
    for (int mt = 0; mt < 8; ++mt) {
      const int m = ss + wm * 128 + mt * 16 + cl;
      #pragma unroll
      for (int nt = 0; nt < 4; ++nt) {
        const int np = npb + nt * 16 + quad * 4;
        const int hh = np >> 6, d0 = np & 63;
        ushort4 pk;
        pk.x = f2bf(acc[mt][nt][0] * sc2);
        pk.y = f2bf(acc[mt][nt][1] * sc2);
        pk.z = f2bf(acc[mt][nt][2] * sc2);
        pk.w = f2bf(acc[mt][nt][3] * sc2);
        *(ushort4*)&dst[((size_t)(bb * 16 + hh) * 2048 + m) * 64 + d0] = pk;
      }
    }
  } else {
    // V (normal orientation): transpose through LDS (reuse pool),
    // trans[128][264] shorts per round; 2 rounds (wn pairs).
    unsigned short* trans = pool;
    #pragma unroll 1
    for (int r = 0; r < 2; ++r) {
      __syncthreads();
      if ((wn >> 1) == r) {
        #pragma unroll
        for (int mt = 0; mt < 8; ++mt) {
          const int s_l = wm * 128 + mt * 16 + quad * 4;
          #pragma unroll
          for (int nt = 0; nt < 4; ++nt) {
            const int n_l = (wn & 1) * 64 + nt * 16 + cl;
            ushort4 pk;
            pk.x = f2bf(acc[mt][nt][0]); pk.y = f2bf(acc[mt][nt][1]);
            pk.z = f2bf(acc[mt][nt][2]); pk.w = f2bf(acc[mt][nt][3]);
            *(ushort4*)&trans[n_l * 264 + s_l] = pk;
          }
        }
      }
      __syncthreads();
      const int row = tid >> 2, q4 = tid & 3;
      const int nv = (n0 & 1023) + r * 128 + row;
      const int hh = nv >> 6, d = nv & 63;
      unsigned short* drow = Vt + ((size_t)(bb * 16 + hh) * 64 + d) * 2048 + ss + q4 * 64;
      #pragma unroll
      for (int i = 0; i < 8; ++i)
        *(bf16x8*)(drow + i * 8) = *(const bf16x8*)&trans[row * 264 + q4 * 64 + i * 8];
    }
  }
}

// ---------------------------------------------------------------------------
// Out-projection (proven 128^2 structure): 4 waves, TRIPLE-buffered K-loop,
// counted vmcnt(4), grid 8x32 = 256 blocks.
// ---------------------------------------------------------------------------
__global__ __launch_bounds__(256) void gemm_obt(const unsigned short* __restrict__ A,
                                                const unsigned short* __restrict__ B,
                                                const float* __restrict__ bias,
                                                float* __restrict__ OutF)
{
  __shared__ unsigned short pool[24576];   // 3 stages x (A 4096 | B 4096) shorts

  const int tid  = threadIdx.x;
  const int wave = tid >> 6, lane = tid & 63, quad = lane >> 4, cl = lane & 15;
  const int wm = wave >> 1, wn = wave & 1;
  const int m0 = blockIdx.y * 128, n0 = blockIdx.x * 128;
  const int sr = lane >> 2, sc = lane & 3;

  f32x4 acc[4][4];
  #pragma unroll
  for (int i = 0; i < 4; ++i)
    #pragma unroll
    for (int j = 0; j < 4; ++j)
      #pragma unroll
      for (int r = 0; r < 4; ++r) acc[i][j][r] = 0.f;

  const int scs = (sc ^ ((sr >> 1) & 3)) * 8;
  const int rchunk = (quad ^ ((cl >> 1) & 3)) * 8;

  auto stage = [&](int k0, int buf) {
    unsigned short* As = pool + buf * 8192;
    unsigned short* Bs = As + 4096;
    #pragma unroll
    for (int ii = 0; ii < 2; ++ii) {
      const int r = wave * 32 + ii * 16 + sr;
      GLDS16(A + (size_t)(m0 + r) * 1024 + k0 + scs, &As[(wave * 32 + ii * 16) * 32]);
      GLDS16(B + (size_t)(n0 + r) * 1024 + k0 + scs, &Bs[(wave * 32 + ii * 16) * 32]);
    }
  };

  stage(0, 0);
  stage(32, 1);
  int cur = 0;
  #pragma unroll 1
  for (int it = 0; it < 32; ++it) {
    if (it + 2 < 32) {
      ASYNC_BAR(4);                              // drain stage(it); keep stage(it+1)
      const int bnx = (cur == 0) ? 2 : cur - 1;  // (cur+2)%3
      stage((it + 2) * 32, bnx);
    } else if (it + 1 < 32) {
      ASYNC_BAR(4);
    } else {
      ASYNC_BAR(0);
    }

    const unsigned short* As = pool + cur * 8192;
    const unsigned short* Bs = As + 4096;
    bf16x8 af[4], bfr[4];
    #pragma unroll
    for (int mt = 0; mt < 4; ++mt)
      af[mt] = *(const bf16x8*)&As[(wm * 64 + mt * 16 + cl) * 32 + rchunk];
    #pragma unroll
    for (int nt = 0; nt < 4; ++nt)
      bfr[nt] = *(const bf16x8*)&Bs[(wn * 64 + nt * 16 + cl) * 32 + rchunk];

    __builtin_amdgcn_s_setprio(1);
    #pragma unroll
    for (int mt = 0; mt < 4; ++mt)
      #pragma unroll
      for (int nt = 0; nt < 4; ++nt)
        acc[mt][nt] = MFMA16(bfr[nt], af[mt], acc[mt][nt]);   // D = C^T
    __builtin_amdgcn_s_setprio(0);
    cur = (cur == 2) ? 0 : cur + 1;
  }

  #pragma unroll
  for (int mt = 0; mt < 4; ++mt) {
    const int m = m0 + wm * 64 + mt * 16 + cl;
    #pragma unroll
    for (int nt = 0; nt < 4; ++nt) {
      const int n = n0 + wn * 64 + nt * 16 + quad * 4;
      const float4 bv = *(const float4*)(bias + n);
      float4 o;
      o.x = acc[mt][nt][0] + bv.x; o.y = acc[mt][nt][1] + bv.y;
      o.z = acc[mt][nt][2] + bv.z; o.w = acc[mt][nt][3] + bv.w;
      *(float4*)&OutF[(size_t)m * 1024 + n] = o;
    }
  }
}

// ---------------------------------------------------------------------------
// Flash attention R21 (=R19): unpaired q-groups (1024 blocks, wave owns group
// G=4p'+w, big-work-first), KVBLK=128 rounds (two 64-j sub-chunks, ONE
// vmcnt(0)+barrier per round, dist-1 round dbuf). P-IN-REGISTERS: the
// pk2bf words ARE the K=16 MFMA A-fragment; PV + row-sum use
// v_mfma_f32_16x16x16_bf16 (two chained per j-32-block). No Psm.
// LDS: Ksm 32KB + Vsm 32KB = 65536B -> 2 blocks/CU.
// ---------------------------------------------------------------------------
__global__ __launch_bounds__(256) void attn_mfma(const unsigned short* __restrict__ Qb,
                                                 const unsigned short* __restrict__ Kb,
                                                 const unsigned short* __restrict__ Vt,
                                                 unsigned short* __restrict__ CTX)
{
  __shared__ unsigned short Ksm[2][2][64 * 64];   // [round buf][sub][64 rows x 128B]
  __shared__ unsigned short Vsm[2][2][64 * 64];

  const int tid  = threadIdx.x;
  const int wave = tid >> 6, lane = tid & 63, quad = lane >> 4, cl = lane & 15;

  const int L  = blockIdx.x;
  const int bh = 4 * (L & 7) + ((L >> 3) & 3);    // XCD-affine: 4 bh per XCD
  const int b  = bh >> 4, h = bh & 15;
  const int pp = 31 - (L >> 5);                   // 0..31, big-work-first
  const int G  = pp * 4 + wave;                   // q-group 0..127
  const int qb = G * 16;
  const size_t base = (size_t)bh * (2048 * 64);

  bf16x8 qf[2];
  #pragma unroll
  for (int dk = 0; dk < 2; ++dk)
    qf[dk] = *(const bf16x8*)(Qb + base + (size_t)(qb + cl) * 64 + dk * 32 + quad * 8);

  f32x4 oacc[4];
  #pragma unroll
  for (int dt = 0; dt < 4; ++dt)
    #pragma unroll
    for (int r = 0; r < 4; ++r) oacc[dt][r] = 0.f;
  float lr[4] = {};

  bf16x4 ones4;
  #pragma unroll
  for (int k = 0; k < 4; ++k) ones4[k] = (short)0x3F80;

  const int lrow  = lane >> 3;
  const int lslot = (lane & 7) ^ lrow;
  const int nch = pp + 1;                          // 64-chunks: 1..32
  const int nrd = (nch + 1) >> 1;                  // 128-rounds: 1..16

  // Stage one 64-j sub-chunk (layout identical to R18).
  auto stageKV = [&](int ch, int buf, int sub) {
    const int j64 = ch * 64;
    #pragma unroll
    for (int ii = 0; ii < 2; ++ii) {
      const int r0 = wave * 16 + ii * 8;
      GLDS16(Kb + base + (size_t)(j64 + r0 + lrow) * 64 + lslot * 8,
             &Ksm[buf][sub][r0 * 64]);
      GLDS16(Vt + base + (size_t)(r0 + lrow) * 2048 + j64 + lslot * 8,
             &Vsm[buf][sub][r0 * 64]);
    }
  };

  // Prologue: round 0 = chunks 0,1 (chunk 1 always within the 2048-row
  // arrays; if unused (pp=0) it is drained by the round-0 ASYNC_BAR(0)).
  stageKV(0, 0, 0);
  stageKV(1, 0, 1);

  #pragma unroll 1
  for (int t = 0; t < nrd; ++t) {
    // Drain round t's 8 GLDS (issued a full round ago; K/V L2-resident) and
    // sync. Barrier also proves all waves are past round t-1's reads of
    // buf[(t+1)&1] -> safe to overwrite.
    ASYNC_BAR(0);
    if (t + 1 < nrd) {
      stageKV(2 * t + 2, (t + 1) & 1, 0);
      stageKV(2 * t + 3, (t + 1) & 1, 1);
    }

    #pragma unroll
    for (int cs = 0; cs < 2; ++cs) {
      const int ch = 2 * t + cs;
      const unsigned short* Kc = Ksm[t & 1][cs];
      const unsigned short* Vc = Vsm[t & 1][cs];
      const int j64c = ch * 64;

      #pragma unroll
      for (int jli = 0; jli < 2; ++jli) {
        const int jg0 = j64c + jli * 32;
        if (jg0 > qb + 15) continue;               // causal skip (covers odd-nch tail)
        const int jl = jli * 32;

        bf16x8 kf[2][2];
        #pragma unroll
        for (int jf = 0; jf < 2; ++jf)
          #pragma unroll
          for (int dk = 0; dk < 2; ++dk) {
            const int jrow = jl + jf * 16 + cl;
            const int slot = (dk * 4 + quad) ^ (cl & 7);
            kf[jf][dk] = *(const bf16x8*)&Kc[jrow * 64 + slot * 8];
          }

        f32x4 st[2];
        __builtin_amdgcn_s_setprio(1);
        #pragma unroll
        for (int jf = 0; jf < 2; ++jf) {
          f32x4 z;
          #pragma unroll
          for (int r = 0; r < 4; ++r) z[r] = 0.f;
          z = MFMA16(kf[jf][0], qf[0], z);
          st[jf] = MFMA16(kf[jf][1], qf[1], z);
        }
        __builtin_amdgcn_s_setprio(0);

        // softmax: P[q=cl][jf*16+quad*4+r] packed to bf16 IN REGISTERS.
        // w[jf] (2 u32 = 4 bf16) is exactly the 16x16x16 A-fragment
        // A[m=cl][k=quad*4+i] for the j-16-block (jl+jf*16).
        const bool diag = (jg0 + 32 > qb);
        uint2 w[2];
        #pragma unroll
        for (int jf = 0; jf < 2; ++jf) {
          float pv[4];
          if (diag) {
            const int qg = qb + cl;
            #pragma unroll
            for (int r = 0; r < 4; ++r) {
              const int jg = jg0 + jf * 16 + quad * 4 + r;
              pv[r] = (jg <= qg) ? EXP2F(st[jf][r]) : 0.f;
            }
          } else {
            #pragma unroll
            for (int r = 0; r < 4; ++r) pv[r] = EXP2F(st[jf][r]);
          }
          w[jf].x = pk2bf(pv[0], pv[1]);
          w[jf].y = pk2bf(pv[2], pv[3]);
        }
        const bf16x4 pf0 = __builtin_bit_cast(bf16x4, w[0]);
        const bf16x4 pf1 = __builtin_bit_cast(bf16x4, w[1]);

        // V fragments for 16x16x16 B[n=d][k=quad*4+i]: j = jl+jf*16+quad*4+i.
        // logical 16B slot = (jl>>3)+jf*2+(quad>>1), 8B half = quad&1;
        // phys slot = logical ^ (d&7) = logical ^ (cl&7)  [same involution].
        bf16x4 vf[2][4];
        #pragma unroll
        for (int jf = 0; jf < 2; ++jf) {
          const int slog = (jl >> 3) + jf * 2 + (quad >> 1);
          const int soff = ((slog ^ (cl & 7)) << 3) + ((quad & 1) << 2);
          #pragma unroll
          for (int dt = 0; dt < 4; ++dt) {
            const int d = dt * 16 + cl;
            vf[jf][dt] = *(const bf16x4*)&Vc[d * 64 + soff];
          }
        }

        __builtin_amdgcn_s_setprio(1);
        {
          f32x4 ls;
          #pragma unroll
          for (int r = 0; r < 4; ++r) ls[r] = 0.f;
          ls = MFMAK16(pf0, ones4, ls);
          ls = MFMAK16(pf1, ones4, ls);
          #pragma unroll
          for (int r = 0; r < 4; ++r) lr[r] += ls[r];
          #pragma unroll
          for (int dt = 0; dt < 4; ++dt) {
            oacc[dt] = MFMAK16(pf0, vf[0][dt], oacc[dt]);
            oacc[dt] = MFMAK16(pf1, vf[1][dt], oacc[dt]);
          }
        }
        __builtin_amdgcn_s_setprio(0);
      }
    }
  }

  {
    float inv[4];
    #pragma unroll
    for (int r = 0; r < 4; ++r) inv[r] = 1.f / lr[r];
    #pragma unroll
    for (int dt = 0; dt < 4; ++dt)
      #pragma unroll
      for (int r = 0; r < 4; ++r)
        CTX[(size_t)(b * 2048 + qb + quad * 4 + r) * 1024 +
            h * 64 + dt * 16 + cl] = f2bf(oacc[dt][r] * inv[r]);
  }
}

// ---------------------------------------------------------------------------
extern "C" void kernel_launch(void* const* d_in, const int* in_sizes, int n_in,
                              void* d_out, int out_size, void* d_ws, size_t ws_size,
                              hipStream_t stream)
{
  const float* x    = (const float*)d_in[0];
  const float* Wqkv = (const float*)d_in[1];
  const float* Wout = (const float*)d_in[2];
  const float* bout = (const float*)d_in[3];
  float* out = (float*)d_out;

  char* ws = (char*)d_ws;
  unsigned short* xb  = (unsigned short*)(ws);
  unsigned short* wqb = (unsigned short*)(ws + 8388608);
  unsigned short* wob = (unsigned short*)(ws + 14680064);
  unsigned short* Qb  = (unsigned short*)(ws + 16777216);
  unsigned short* Kb  = (unsigned short*)(ws + 25165824);
  unsigned short* Vt  = (unsigned short*)(ws + 33554432);
  unsigned short* CTX = (unsigned short*)(ws + 41943040);

  cast_bf16<<<dim3(8192), dim3(256), 0, stream>>>(x, Wqkv, Wout, xb, wqb, wob);

  // QKV projection: M=4096, N=3072, K=1024 -- 256^2 tile, 192 blocks
  gemm_qkv<<<dim3(192), dim3(512), 0, stream>>>(xb, wqb, Qb, Kb, Vt);

  // Flash attention: 1024 blocks (32 bh x 32 p'), 4 waves, KVBLK=128 rounds
  attn_mfma<<<dim3(1024), dim3(256), 0, stream>>>(Qb, Kb, Vt, CTX);

  // Output projection: M=4096, N=1024, K=1024, + bias (proven 128^2 kernel)
  gemm_obt<<<dim3(8, 32), dim3(256), 0, stream>>>(CTX, wob, bout, out);
}

// Round 12
// 175.003 us; speedup vs baseline: 1.0878x; 1.0529x over previous
//
#include <hip/hip_runtime.h>
#include <cstdint>
#include <cstddef>

// MultiHeadAttention R22:
//   gemm_qkv unchanged (256x256 8-wave phase-split, 3-bit XOR swizzle).
//   gemm_obt unchanged (proven 128^2 out-proj).
//   attn_mfma: J-SPLIT. Evidence: nine attn variants pinned 49-52us; R21
//   showed makespan == longest block's serial walk (pp=31: 16 rounds x
//   3.06us/round = 49us, ~2.8us/round is COMPUTE). No micro-opt touches a
//   compute-serial critical path -> parallelize along j. No-max softmax
//   partials over disjoint j-ranges are ADDITIVE (oacc, lr are pure sums),
//   so: 8-wave blocks (512 thr), same 4 groups (uniform nch = pp+1), wave
//   (g = w&3, s = w>>2) computes only chunks 2t+s. Staging UNCHANGED and
//   shared (KVBLK=128 dbuf, 4 GLDS/thread/round at wave*8 rows) -> L2
//   volume unchanged. Critical path ~halves. End: s=1 partials -> LDS
//   (aliased over Ksm after a barrier), s=0 adds + normalizes + writes CTX.
//   Keeps R21's P-in-registers K=16 PV (no Psm).
// ws layout (bytes):
//   xb @0 [4096][1024] bf16 | wqb @8388608 [3072][1024] | wob @14680064 [1024][1024]
//   Qb @16777216, Kb @25165824: [2][16][2048][64] bf16 (Qb = Q*log2e)
//   Vt @33554432: [2][16][64][2048] bf16 (transposed)
//   CTX @41943040 [4096][1024] bf16
// MFMA 16x16x32_bf16 frags: A[m=lane&15][k=quad*8+i], B[n=lane&15][k=quad*8+i],
// C/D[row=quad*4+reg][col=lane&15]. 16x16x16: k=quad*4+i, same C/D.
// Swapped operands -> D = C^T.

typedef __attribute__((ext_vector_type(8))) short bf16x8;
typedef __attribute__((ext_vector_type(4))) short bf16x4;
typedef __attribute__((ext_vector_type(4))) float f32x4;

#define LOG2E 1.44269504f

#define MFMA16(a, b, c) __builtin_amdgcn_mfma_f32_16x16x32_bf16((a), (b), (c), 0, 0, 0)

// K=16 bf16 MFMA: guard must only run in the DEVICE pass -- __has_builtin
// returns false for amdgcn builtins during hipcc's host pass (R10 lesson).
#if defined(__HIP_DEVICE_COMPILE__)
  #if __has_builtin(__builtin_amdgcn_mfma_f32_16x16x16bf16_1k)
    #define MFMAK16(a, b, c) __builtin_amdgcn_mfma_f32_16x16x16bf16_1k((a), (b), (c), 0, 0, 0)
  #elif __has_builtin(__builtin_amdgcn_mfma_f32_16x16x16_bf16)
    #define MFMAK16(a, b, c) __builtin_amdgcn_mfma_f32_16x16x16_bf16((a), (b), (c), 0, 0, 0)
  #else
    #error "no 16x16x16 bf16 MFMA builtin on device"
  #endif
#else
  #define MFMAK16(a, b, c) (c)   // host pass: parsed, never executed
#endif

#define GLDS16(g, s)                                                        \
  __builtin_amdgcn_global_load_lds(                                         \
      (const __attribute__((address_space(1))) void*)(g),                   \
      (__attribute__((address_space(3))) void*)(s), 16, 0, 0)

// Manual barrier: wait until <= N vector-memory ops outstanding, then barrier.
// ONLY valid when the loop's vmem traffic is exclusively the staged GLDS.
#define ASYNC_BAR(N) asm volatile("s_waitcnt vmcnt(" #N ")\n\ts_barrier" ::: "memory")
#define BAR() asm volatile("s_barrier" ::: "memory")

// Native 2^x: v_exp_f32 (gfx950 VOP1). Input already in log2 domain.
static __device__ __forceinline__ float exp2_hw(float x) {
  float r;
  asm("v_exp_f32 %0, %1" : "=v"(r) : "v"(x));
  return r;
}
#define EXP2F(x) exp2_hw(x)

static __device__ __forceinline__ unsigned short f2bf(float f) {  // RNE
  unsigned int u = __builtin_bit_cast(unsigned int, f);
  u += 0x7FFFu + ((u >> 16) & 1u);
  return (unsigned short)(u >> 16);
}

// pack two fp32 -> two bf16 (round-nearest) in one u32: 2 add + 1 perm
static __device__ __forceinline__ unsigned int pk2bf(float a, float b) {
  const unsigned int ua = __builtin_bit_cast(unsigned int, a) + 0x8000u;
  const unsigned int ub = __builtin_bit_cast(unsigned int, b) + 0x8000u;
  return __builtin_amdgcn_perm(ub, ua, 0x07060302);
}

// ---------------------------------------------------------------------------
__global__ __launch_bounds__(256) void cast_bf16(const float* __restrict__ x,
                                                 const float* __restrict__ wq,
                                                 const float* __restrict__ wo,
                                                 unsigned short* __restrict__ xb,
                                                 unsigned short* __restrict__ wqb,
                                                 unsigned short* __restrict__ wob)
{
  const int id = blockIdx.x * 256 + threadIdx.x;
  const float* src;
  unsigned short* dst;
  int off;
  if (id < 1048576)               { src = x;  dst = xb;  off = id; }
  else if (id < 1048576 + 786432) { src = wq; dst = wqb; off = id - 1048576; }
  else                            { src = wo; dst = wob; off = id - (1048576 + 786432); }
  float4 v = ((const float4*)src)[off];
  ushort4 o;
  o.x = f2bf(v.x); o.y = f2bf(v.y); o.z = f2bf(v.z); o.w = f2bf(v.w);
  ((ushort4*)dst)[off] = o;
}

// ---------------------------------------------------------------------------
// QKV GEMM (unchanged R12): 256x256 tile, BK=64, 512 threads = 8 waves
// (2M x 4N), per-wave 128x64 output (acc[8][4] of 16x16 frags).
// LDS 128 KiB: 2 buffers x (A 256x64 | B 256x64) bf16, rows of 128B split
// into 8x16B slots, phys_slot = logical_slot ^ (row & 7)   [FULL 3-bit XOR].
// 4 phases per K-tile, 16 MFMA each; ONE vmcnt(4) per K-tile.
// ---------------------------------------------------------------------------
#define MMAC(AF, BF, MS, NS)                                                       \
  do {                                                                             \
    __builtin_amdgcn_s_setprio(1);                                                 \
    if (swapped) {                                                                 \
      _Pragma("unroll")                                                            \
      for (int mt = 0; mt < 4; ++mt)                                               \
        _Pragma("unroll")                                                          \
        for (int nt = 0; nt < 2; ++nt) {                                           \
          acc[(MS)*4+mt][(NS)*2+nt] = MFMA16(BF[nt][0], AF[mt][0], acc[(MS)*4+mt][(NS)*2+nt]); \
          acc[(MS)*4+mt][(NS)*2+nt] = MFMA16(BF[nt][1], AF[mt][1], acc[(MS)*4+mt][(NS)*2+nt]); \
        }                                                                          \
    } else {                                                                       \
      _Pragma("unroll")                                                            \
      for (int mt = 0; mt < 4; ++mt)                                               \
        _Pragma("unroll")                                                          \
        for (int nt = 0; nt < 2; ++nt) {                                           \
          acc[(MS)*4+mt][(NS)*2+nt] = MFMA16(AF[mt][0], BF[nt][0], acc[(MS)*4+mt][(NS)*2+nt]); \
          acc[(MS)*4+mt][(NS)*2+nt] = MFMA16(AF[mt][1], BF[nt][1], acc[(MS)*4+mt][(NS)*2+nt]); \
        }                                                                          \
    }                                                                              \
    __builtin_amdgcn_s_setprio(0);                                                 \
  } while (0)

__global__ __launch_bounds__(512, 2) void gemm_qkv(const unsigned short* __restrict__ A,
                                                   const unsigned short* __restrict__ B,
                                                   unsigned short* __restrict__ Qb,
                                                   unsigned short* __restrict__ Kb,
                                                   unsigned short* __restrict__ Vt)
{
  // shorts: buf b: A @ b*32768 (256 rows x 64), B @ b*32768+16384. 128 KiB.
  __shared__ unsigned short pool[65536];

  const int tid  = threadIdx.x;
  const int wave = tid >> 6, lane = tid & 63, quad = lane >> 4, cl = lane & 15;
  const int wm = wave >> 2, wn = wave & 3;

  // Bijective XCD chunking: 192 blocks, 24/XCD covering a 4(mb) x 6(nb) chunk.
  const int bid = blockIdx.x;
  const int xcd = bid & 7, j = bid >> 3;
  const int mb = (xcd >> 1) * 4 + j / 6;
  const int nb = (xcd & 1) * 6 + j % 6;
  const int m0 = mb * 256, n0 = nb * 256;
  const int part = nb >> 2;                 // 0=Q 1=K 2=V
  const bool swapped = (part < 2);

  // --- staging: per GLDS16, wave covers 8 rows x 128B linearly.
  // lane l -> row r0+(l>>3), phys slot l&7. Pre-swizzled global source:
  // logical slot = phys ^ (row&7) = (l&7) ^ (l>>3)   [r0 is a multiple of 8]
  const int lrow = lane >> 3;
  const int sg   = (lane & 7) ^ lrow;

  auto stageA = [&](int h0, int buf, int k0) {
    #pragma unroll
    for (int ii = 0; ii < 2; ++ii) {
      const int r0 = h0 + wave * 16 + ii * 8;
      GLDS16(A + (size_t)(m0 + r0 + lrow) * 1024 + k0 + sg * 8,
             &pool[buf * 32768 + r0 * 64]);
    }
  };
  auto stageB = [&](int h0, int buf, int k0) {
    #pragma unroll
    for (int ii = 0; ii < 2; ++ii) {
      const int r0 = h0 + wave * 16 + ii * 8;
      GLDS16(B + (size_t)(n0 + r0 + lrow) * 1024 + k0 + sg * 8,
             &pool[buf * 32768 + 16384 + r0 * 64]);
    }
  };

  // --- fragment reads: row = 16-aligned base + cl -> row&7 == cl&7.
  // logical k-chunk (kk*4+quad) lives at phys slot (kk*4+quad) ^ (cl&7).
  const int rswz = cl & 7;
  auto loadA = [&](bf16x8 (&af)[4][2], int msub, int b) {
    const unsigned short* base = &pool[b * 32768];
    #pragma unroll
    for (int mt = 0; mt < 4; ++mt) {
      const int row = wm * 128 + msub * 64 + mt * 16 + cl;
      #pragma unroll
      for (int kk = 0; kk < 2; ++kk)
        af[mt][kk] = *(const bf16x8*)&base[row * 64 + ((kk * 4 + quad) ^ rswz) * 8];
    }
  };
  auto loadB = [&](bf16x8 (&bf)[2][2], int nsub, int b) {
    const unsigned short* base = &pool[b * 32768 + 16384];
    #pragma unroll
    for (int nt = 0; nt < 2; ++nt) {
      const int row = wn * 64 + nsub * 32 + nt * 16 + cl;
      #pragma unroll
      for (int kk = 0; kk < 2; ++kk)
        bf[nt][kk] = *(const bf16x8*)&base[row * 64 + ((kk * 4 + quad) ^ rswz) * 8];
    }
  };

  f32x4 acc[8][4];
  #pragma unroll
  for (int i = 0; i < 8; ++i)
    #pragma unroll
    for (int jj = 0; jj < 4; ++jj)
      #pragma unroll
      for (int r = 0; r < 4; ++r) acc[i][jj][r] = 0.f;

  // Prologue: all 4 half-tiles of tile0, then lo halves of tile1 (12 loads).
  stageB(0,   0, 0);
  stageA(0,   0, 0);
  stageB(128, 0, 0);
  stageA(128, 0, 0);
  stageB(0,   1, 64);
  stageA(0,   1, 64);

  #pragma unroll 1
  for (int t = 0; t < 16; ++t) {
    const int b = t & 1, bn = b ^ 1;
    const int kc  = (t + 1) * 64;
    const int kc2 = (t + 2) * 64;

    bf16x8 af[4][2], bfA[2][2], bfB[2][2];

    // P0: quadrant (0,0). vmcnt(4): guarantees all 4 halves of tile t
    // (newest needed = A-hi(t) @ (t-1)-P1; newer in flight = B-lo/A-lo(t+1)).
    if (t < 15) { ASYNC_BAR(4); } else { ASYNC_BAR(0); }
    loadA(af, 0, b);
    loadB(bfA, 0, b);
    if (t < 15) stageB(128, bn, kc);       // B-hi(t+1)
    MMAC(af, bfA, 0, 0);

    // P1: quadrant (0,1). No barrier needed: reads tile-t B (published at P0),
    // GLDS writes buffer bn (not being read).
    loadB(bfB, 1, b);
    if (t < 15) stageA(128, bn, kc);       // A-hi(t+1)
    MMAC(af, bfB, 0, 1);

    // P2: quadrant (1,1). Barrier: B-lo(t+2) overwrites B-lo(b) whose last
    // reads were P1 (other waves).
    BAR();
    loadA(af, 1, b);
    if (t < 14) stageB(0, b, kc2);         // B-lo(t+2)
    MMAC(af, bfB, 1, 1);

    // P3: quadrant (1,0), reuses bfA regs. Barrier: A-lo(t+2) overwrites
    // A-lo(b) whose last reads were P2 (wm=0 waves).
    BAR();
    if (t < 14) stageA(0, b, kc2);         // A-lo(t+2)
    MMAC(af, bfA, 1, 0);
  }
  // ASYNC_BAR(0) at t=15-P0 drained all staging: no GLDS in flight here.

  const int bb = m0 >> 11, ss = m0 & 2047;
  if (part < 2) {
    // Q/K (swapped: D=C^T): lane holds 4 consecutive d for one s -> ushort4
    unsigned short* dst = (part == 0) ? Qb : Kb;
    const float sc2 = (part == 0) ? LOG2E : 1.0f;
    const int npb = (n0 & 1023) + wn * 64;
    #pragma unroll
    for (int mt = 0; mt < 8; ++mt) {
      const int m = ss + wm * 128 + mt * 16 + cl;
      #pragma unroll
      for (int nt = 0; nt < 4; ++nt) {
        const int np = npb + nt * 16 + quad * 4;
        const int hh = np >> 6, d0 = np & 63;
        ushort4 pk;
        pk.x = f2bf(acc[mt][nt][0] * sc2);
        pk.y = f2bf(acc[mt][nt][1] * sc2);
        pk.z = f2bf(acc[mt][nt][2] * sc2);
        pk.w = f2bf(acc[mt][nt][3] * sc2);
        *(ushort4*)&dst[((size_t)(bb * 16 + hh) * 2048 + m) * 64 + d0] = pk;
      }
    }
  } else {
    // V (normal orientation): transpose through LDS (reuse pool),
    // trans[128][264] shorts per round; 2 rounds (wn pairs).
    unsigned short* trans = pool;
    #pragma unroll 1
    for (int r = 0; r < 2; ++r) {
      __syncthreads();
      if ((wn >> 1) == r) {
        #pragma unroll
        for (int mt = 0; mt < 8; ++mt) {
          const int s_l = wm * 128 + mt * 16 + quad * 4;
          #pragma unroll
          for (int nt = 0; nt < 4; ++nt) {
            const int n_l = (wn & 1) * 64 + nt * 16 + cl;
            ushort4 pk;
            pk.x = f2bf(acc[mt][nt][0]); pk.y = f2bf(acc[mt][nt][1]);
            pk.z = f2bf(acc[mt][nt][2]); pk.w = f2bf(acc[mt][nt][3]);
            *(ushort4*)&trans[n_l * 264 + s_l] = pk;
          }
        }
      }
      __syncthreads();
      const int row = tid >> 2, q4 = tid & 3;
      const int nv = (n0 & 1023) + r * 128 + row;
      const int hh = nv >> 6, d = nv & 63;
      unsigned short* drow = Vt + ((size_t)(bb * 16 + hh) * 64 + d) * 2048 + ss + q4 * 64;
      #pragma unroll
      for (int i = 0; i < 8; ++i)
        *(bf16x8*)(drow + i * 8) = *(const bf16x8*)&trans[row * 264 + q4 * 64 + i * 8];
    }
  }
}

// ---------------------------------------------------------------------------
// Out-projection (proven 128^2 structure): 4 waves, TRIPLE-buffered K-loop,
// counted vmcnt(4), grid 8x32 = 256 blocks.
// ---------------------------------------------------------------------------
__global__ __launch_bounds__(256) void gemm_obt(const unsigned short* __restrict__ A,
                                                const unsigned short* __restrict__ B,
                                                const float* __restrict__ bias,
                                                float* __restrict__ OutF)
{
  __shared__ unsigned short pool[24576];   // 3 stages x (A 4096 | B 4096) shorts

  const int tid  = threadIdx.x;
  const int wave = tid >> 6, lane = tid & 63, quad = lane >> 4, cl = lane & 15;
  const int wm = wave >> 1, wn = wave & 1;
  const int m0 = blockIdx.y * 128, n0 = blockIdx.x * 128;
  const int sr = lane >> 2, sc = lane & 3;

  f32x4 acc[4][4];
  #pragma unroll
  for (int i = 0; i < 4; ++i)
    #pragma unroll
    for (int j = 0; j < 4; ++j)
      #pragma unroll
      for (int r = 0; r < 4; ++r) acc[i][j][r] = 0.f;

  const int scs = (sc ^ ((sr >> 1) & 3)) * 8;
  const int rchunk = (quad ^ ((cl >> 1) & 3)) * 8;

  auto stage = [&](int k0, int buf) {
    unsigned short* As = pool + buf * 8192;
    unsigned short* Bs = As + 4096;
    #pragma unroll
    for (int ii = 0; ii < 2; ++ii) {
      const int r = wave * 32 + ii * 16 + sr;
      GLDS16(A + (size_t)(m0 + r) * 1024 + k0 + scs, &As[(wave * 32 + ii * 16) * 32]);
      GLDS16(B + (size_t)(n0 + r) * 1024 + k0 + scs, &Bs[(wave * 32 + ii * 16) * 32]);
    }
  };

  stage(0, 0);
  stage(32, 1);
  int cur = 0;
  #pragma unroll 1
  for (int it = 0; it < 32; ++it) {
    if (it + 2 < 32) {
      ASYNC_BAR(4);                              // drain stage(it); keep stage(it+1)
      const int bnx = (cur == 0) ? 2 : cur - 1;  // (cur+2)%3
      stage((it + 2) * 32, bnx);
    } else if (it + 1 < 32) {
      ASYNC_BAR(4);
    } else {
      ASYNC_BAR(0);
    }

    const unsigned short* As = pool + cur * 8192;
    const unsigned short* Bs = As + 4096;
    bf16x8 af[4], bfr[4];
    #pragma unroll
    for (int mt = 0; mt < 4; ++mt)
      af[mt] = *(const bf16x8*)&As[(wm * 64 + mt * 16 + cl) * 32 + rchunk];
    #pragma unroll
    for (int nt = 0; nt < 4; ++nt)
      bfr[nt] = *(const bf16x8*)&Bs[(wn * 64 + nt * 16 + cl) * 32 + rchunk];

    __builtin_amdgcn_s_setprio(1);
    #pragma unroll
    for (int mt = 0; mt < 4; ++mt)
      #pragma unroll
      for (int nt = 0; nt < 4; ++nt)
        acc[mt][nt] = MFMA16(bfr[nt], af[mt], acc[mt][nt]);   // D = C^T
    __builtin_amdgcn_s_setprio(0);
    cur = (cur == 2) ? 0 : cur + 1;
  }

  #pragma unroll
  for (int mt = 0; mt < 4; ++mt) {
    const int m = m0 + wm * 64 + mt * 16 + cl;
    #pragma unroll
    for (int nt = 0; nt < 4; ++nt) {
      const int n = n0 + wn * 64 + nt * 16 + quad * 4;
      const float4 bv = *(const float4*)(bias + n);
      float4 o;
      o.x = acc[mt][nt][0] + bv.x; o.y = acc[mt][nt][1] + bv.y;
      o.z = acc[mt][nt][2] + bv.z; o.w = acc[mt][nt][3] + bv.w;
      *(float4*)&OutF[(size_t)m * 1024 + n] = o;
    }
  }
}

// ---------------------------------------------------------------------------
// Flash attention R22: 8-wave blocks (512 thr), 4 groups (G=4p'+g, uniform
// nch = p'+1), 2-way j-split: wave (g = w&3, s = w>>2) computes chunks 2t+s.
// KVBLK=128 rounds, shared dbuf staging (8 waves x 8 rows each), ONE
// vmcnt(0)+barrier per round. P-in-registers K=16 PV (R21). End: s=1 waves
// write partial (oacc, lr) to LDS scratch (aliased over Ksm, after a
// barrier), s=0 waves add + normalize + write CTX. Additivity is exact:
// no-max softmax partials are pure sums.
// LDS: Ksm 32KB + Vsm 32KB = 65536B -> 2 blocks/CU (16 waves/CU).
// ---------------------------------------------------------------------------
__global__ __launch_bounds__(512) void attn_mfma(const unsigned short* __restrict__ Qb,
                                                 const unsigned short* __restrict__ Kb,
                                                 const unsigned short* __restrict__ Vt,
                                                 unsigned short* __restrict__ CTX)
{
  __shared__ unsigned short Ksm[2][2][64 * 64];   // [round buf][sub][64 rows x 128B]
  __shared__ unsigned short Vsm[2][2][64 * 64];

  const int tid  = threadIdx.x;
  const int wave = tid >> 6, lane = tid & 63, quad = lane >> 4, cl = lane & 15;
  const int g = wave & 3, sp = wave >> 2;         // group-slot, j-split index

  const int L  = blockIdx.x;
  const int bh = 4 * (L & 7) + ((L >> 3) & 3);    // XCD-affine: 4 bh per XCD
  const int b  = bh >> 4, h = bh & 15;
  const int pp = 31 - (L >> 5);                   // 0..31, big-work-first
  const int G  = pp * 4 + g;                      // q-group 0..127
  const int qb = G * 16;
  const size_t base = (size_t)bh * (2048 * 64);

  bf16x8 qf[2];
  #pragma unroll
  for (int dk = 0; dk < 2; ++dk)
    qf[dk] = *(const bf16x8*)(Qb + base + (size_t)(qb + cl) * 64 + dk * 32 + quad * 8);

  f32x4 oacc[4];
  #pragma unroll
  for (int dt = 0; dt < 4; ++dt)
    #pragma unroll
    for (int r = 0; r < 4; ++r) oacc[dt][r] = 0.f;
  float lr[4] = {};

  bf16x4 ones4;
  #pragma unroll
  for (int k = 0; k < 4; ++k) ones4[k] = (short)0x3F80;

  const int lrow  = lane >> 3;
  const int lslot = (lane & 7) ^ lrow;
  const int nch = pp + 1;                          // 64-chunks: 1..32
  const int nrd = (nch + 1) >> 1;                  // 128-rounds: 1..16

  // Stage one 64-j sub-chunk, 8 waves x 8 rows each (row = wave*8 + lrow).
  auto stageKV = [&](int ch, int buf, int sub) {
    const int j64 = ch * 64;
    const int r0 = wave * 8;
    GLDS16(Kb + base + (size_t)(j64 + r0 + lrow) * 64 + lslot * 8,
           &Ksm[buf][sub][r0 * 64]);
    GLDS16(Vt + base + (size_t)(r0 + lrow) * 2048 + j64 + lslot * 8,
           &Vsm[buf][sub][r0 * 64]);
  };

  // Prologue: round 0 = chunks 0,1 (chunk 1 always within the 2048-row
  // arrays; if unused (pp=0) it is drained by the round-0 ASYNC_BAR(0)).
  stageKV(0, 0, 0);
  stageKV(1, 0, 1);

  #pragma unroll 1
  for (int t = 0; t < nrd; ++t) {
    // Drain round t's 4 GLDS (issued a full round ago; K/V L2-resident) and
    // sync. Barrier also proves all waves are past round t-1's reads of
    // buf[(t+1)&1] -> safe to overwrite.
    ASYNC_BAR(0);
    if (t + 1 < nrd) {
      stageKV(2 * t + 2, (t + 1) & 1, 0);
      stageKV(2 * t + 3, (t + 1) & 1, 1);
    }

    // This wave computes ONLY chunk 2t+sp for its group.
    {
      const int ch = 2 * t + sp;
      const unsigned short* Kc = Ksm[t & 1][sp];
      const unsigned short* Vc = Vsm[t & 1][sp];
      const int j64c = ch * 64;

      #pragma unroll
      for (int jli = 0; jli < 2; ++jli) {
        const int jg0 = j64c + jli * 32;
        if (jg0 > qb + 15) continue;               // causal skip (covers ch>=nch too)
        const int jl = jli * 32;

        bf16x8 kf[2][2];
        #pragma unroll
        for (int jf = 0; jf < 2; ++jf)
          #pragma unroll
          for (int dk = 0; dk < 2; ++dk) {
            const int jrow = jl + jf * 16 + cl;
            const int slot = (dk * 4 + quad) ^ (cl & 7);
            kf[jf][dk] = *(const bf16x8*)&Kc[jrow * 64 + slot * 8];
          }

        f32x4 st[2];
        __builtin_amdgcn_s_setprio(1);
        #pragma unroll
        for (int jf = 0; jf < 2; ++jf) {
          f32x4 z;
          #pragma unroll
          for (int r = 0; r < 4; ++r) z[r] = 0.f;
          z = MFMA16(kf[jf][0], qf[0], z);
          st[jf] = MFMA16(kf[jf][1], qf[1], z);
        }
        __builtin_amdgcn_s_setprio(0);

        // softmax: P[q=cl][jf*16+quad*4+r] packed to bf16 IN REGISTERS.
        // w[jf] (2 u32 = 4 bf16) is exactly the 16x16x16 A-fragment
        // A[m=cl][k=quad*4+i] for the j-16-block (jl+jf*16).
        const bool diag = (jg0 + 32 > qb);
        uint2 w[2];
        #pragma unroll
        for (int jf = 0; jf < 2; ++jf) {
          float pv[4];
          if (diag) {
            const int qg = qb + cl;
            #pragma unroll
            for (int r = 0; r < 4; ++r) {
              const int jg = jg0 + jf * 16 + quad * 4 + r;
              pv[r] = (jg <= qg) ? EXP2F(st[jf][r]) : 0.f;
            }
          } else {
            #pragma unroll
            for (int r = 0; r < 4; ++r) pv[r] = EXP2F(st[jf][r]);
          }
          w[jf].x = pk2bf(pv[0], pv[1]);
          w[jf].y = pk2bf(pv[2], pv[3]);
        }
        const bf16x4 pf0 = __builtin_bit_cast(bf16x4, w[0]);
        const bf16x4 pf1 = __builtin_bit_cast(bf16x4, w[1]);

        // V fragments for 16x16x16 B[n=d][k=quad*4+i]: j = jl+jf*16+quad*4+i.
        // logical 16B slot = (jl>>3)+jf*2+(quad>>1), 8B half = quad&1;
        // phys slot = logical ^ (d&7) = logical ^ (cl&7)  [same involution].
        bf16x4 vf[2][4];
        #pragma unroll
        for (int jf = 0; jf < 2; ++jf) {
          const int slog = (jl >> 3) + jf * 2 + (quad >> 1);
          const int soff = ((slog ^ (cl & 7)) << 3) + ((quad & 1) << 2);
          #pragma unroll
          for (int dt = 0; dt < 4; ++dt) {
            const int d = dt * 16 + cl;
            vf[jf][dt] = *(const bf16x4*)&Vc[d * 64 + soff];
          }
        }

        __builtin_amdgcn_s_setprio(1);
        {
          f32x4 ls;
          #pragma unroll
          for (int r = 0; r < 4; ++r) ls[r] = 0.f;
          ls = MFMAK16(pf0, ones4, ls);
          ls = MFMAK16(pf1, ones4, ls);
          #pragma unroll
          for (int r = 0; r < 4; ++r) lr[r] += ls[r];
          #pragma unroll
          for (int dt = 0; dt < 4; ++dt) {
            oacc[dt] = MFMAK16(pf0, vf[0][dt], oacc[dt]);
            oacc[dt] = MFMAK16(pf1, vf[1][dt], oacc[dt]);
          }
        }
        __builtin_amdgcn_s_setprio(0);
      }
    }
  }

  // --- cross-split reduction: O = O_s0 + O_s1, l = l_s0 + l_s1 (exact:
  // no-max softmax partials are pure sums). Scratch aliases Ksm; the
  // barrier below orders it after the last K/V reads.
  __syncthreads();
  float* scr = reinterpret_cast<float*>(&Ksm[0][0][0]);   // 4*64*20*4B = 20KB
  const int si = (g * 64 + lane) * 20;
  if (sp == 1) {
    #pragma unroll
    for (int dt = 0; dt < 4; ++dt)
      *(f32x4*)&scr[si + dt * 4] = oacc[dt];
    #pragma unroll
    for (int r = 0; r < 4; ++r) scr[si + 16 + r] = lr[r];
  }
  __syncthreads();
  if (sp == 0) {
    #pragma unroll
    for (int dt = 0; dt < 4; ++dt) {
      const f32x4 o2 = *(const f32x4*)&scr[si + dt * 4];
      #pragma unroll
      for (int r = 0; r < 4; ++r) oacc[dt][r] += o2[r];
    }
    float inv[4];
    #pragma unroll
    for (int r = 0; r < 4; ++r) inv[r] = 1.f / (lr[r] + scr[si + 16 + r]);
    #pragma unroll
    for (int dt = 0; dt < 4; ++dt)
      #pragma unroll
      for (int r = 0; r < 4; ++r)
        CTX[(size_t)(b * 2048 + qb + quad * 4 + r) * 1024 +
            h * 64 + dt * 16 + cl] = f2bf(oacc[dt][r] * inv[r]);
  }
}

// ---------------------------------------------------------------------------
extern "C" void kernel_launch(void* const* d_in, const int* in_sizes, int n_in,
                              void* d_out, int out_size, void* d_ws, size_t ws_size,
                              hipStream_t stream)
{
  const float* x    = (const float*)d_in[0];
  const float* Wqkv = (const float*)d_in[1];
  const float* Wout = (const float*)d_in[2];
  const float* bout = (const float*)d_in[3];
  float* out = (float*)d_out;

  char* ws = (char*)d_ws;
  unsigned short* xb  = (unsigned short*)(ws);
  unsigned short* wqb = (unsigned short*)(ws + 8388608);
  unsigned short* wob = (unsigned short*)(ws + 14680064);
  unsigned short* Qb  = (unsigned short*)(ws + 16777216);
  unsigned short* Kb  = (unsigned short*)(ws + 25165824);
  unsigned short* Vt  = (unsigned short*)(ws + 33554432);
  unsigned short* CTX = (unsigned short*)(ws + 41943040);

  cast_bf16<<<dim3(8192), dim3(256), 0, stream>>>(x, Wqkv, Wout, xb, wqb, wob);

  // QKV projection: M=4096, N=3072, K=1024 -- 256^2 tile, 192 blocks
  gemm_qkv<<<dim3(192), dim3(512), 0, stream>>>(xb, wqb, Qb, Kb, Vt);

  // Flash attention: 1024 blocks (32 bh x 32 p'), 8 waves, 2-way j-split
  attn_mfma<<<dim3(1024), dim3(512), 0, stream>>>(Qb, Kb, Vt, CTX);

  // Output projection: M=4096, N=1024, K=1024, + bias (proven 128^2 kernel)
  gemm_obt<<<dim3(8, 32), dim3(256), 0, stream>>>(CTX, wob, bout, out);
}